// Round 1
// baseline (1087.337 us; speedup 1.0000x reference)
//
#include <hip/hip_runtime.h>
#include <hip/hip_bf16.h>

#define HH 128   // hidden dim

// ---------------- CSR build ----------------

__global__ void count_k(const int* __restrict__ dst, int* __restrict__ cnt, int E) {
    int e = blockIdx.x * 256 + threadIdx.x;
    if (e < E) atomicAdd(&cnt[dst[e]], 1);
}

__global__ void scan1(const int* __restrict__ cnt, int* __restrict__ loc,
                      int* __restrict__ bsums, int N) {
    __shared__ int s[256];
    int i = blockIdx.x * 256 + threadIdx.x;
    int v = (i < N) ? cnt[i] : 0;
    s[threadIdx.x] = v;
    __syncthreads();
    for (int o = 1; o < 256; o <<= 1) {
        int t = (threadIdx.x >= o) ? s[threadIdx.x - o] : 0;
        __syncthreads();
        s[threadIdx.x] += t;
        __syncthreads();
    }
    if (i < N) loc[i] = s[threadIdx.x] - v;          // block-local exclusive
    if (threadIdx.x == 255) bsums[blockIdx.x] = s[255];
}

__global__ void scan2(int* __restrict__ bs, int NB) {
    __shared__ int s[1024];
    int t = threadIdx.x;
    int v = (t < NB) ? bs[t] : 0;
    s[t] = v;
    __syncthreads();
    for (int o = 1; o < 1024; o <<= 1) {
        int tv = (t >= o) ? s[t - o] : 0;
        __syncthreads();
        s[t] += tv;
        __syncthreads();
    }
    if (t < NB) bs[t] = s[t] - v;                    // exclusive over block sums
}

__global__ void scan3(const int* __restrict__ cnt, int* __restrict__ offs,
                      const int* __restrict__ bs, int* __restrict__ cursor,
                      float* __restrict__ invd, int N, int E) {
    int i = blockIdx.x * 256 + threadIdx.x;
    if (i < N) {
        int o = offs[i] + bs[blockIdx.x];
        offs[i] = o;
        cursor[i] = o;
        int d = cnt[i];
        invd[i] = 1.0f / (float)(d > 1 ? d : 1);
    }
    if (i == 0) offs[N] = E;
}

__global__ void scatter_k(const int* __restrict__ src, const int* __restrict__ dst,
                          int* __restrict__ cursor, int* __restrict__ csr, int E) {
    int e = blockIdx.x * 256 + threadIdx.x;
    if (e < E) {
        int d = dst[e];
        int p = atomicAdd(&cursor[d], 1);
        csr[p] = src[e];
    }
}

// ---------------- node encoder: h = relu(x @ encW + encb) ----------------

__global__ __launch_bounds__(256) void encoder_k(
    const float* __restrict__ x, const float* __restrict__ W,
    const float* __restrict__ b, float* __restrict__ h, int N) {
    int n = blockIdx.x * 2 + (threadIdx.x >> 7);
    int j = threadIdx.x & 127;
    if (n >= N) return;
    float v = b[j];
#pragma unroll
    for (int k = 0; k < 4; k++) v = fmaf(x[n * 4 + k], W[k * HH + j], v);
    h[(size_t)n * HH + j] = fmaxf(v, 0.0f);
}

// ---------------- mean aggregation over in-neighbors ----------------

__global__ __launch_bounds__(256) void aggregate_k(
    const float* __restrict__ h, const int* __restrict__ offs,
    const int* __restrict__ csr, const float* __restrict__ invd,
    float* __restrict__ agg, int N) {
    int n = blockIdx.x * 2 + (threadIdx.x >> 7);
    int j = threadIdx.x & 127;
    if (n >= N) return;
    int s = offs[n], e = offs[n + 1];
    float acc = 0.0f;
    for (int i = s; i < e; i++) {
        int u = csr[i];
        acc += h[(size_t)u * HH + j];
    }
    agg[(size_t)n * HH + j] = acc * invd[n];
}

// ---------------- fused SAGE layer: h += relu(LN(agg@Wl + bl + h@Wr)) ----------------
// tile: 64 rows x 128 cols, K = 256 ([agg | h] x [Wl ; Wr]); 256 threads
// thread layout: tc = tid&31 -> cols 4*tc..4*tc+3 ; tr = tid>>5 -> rows tr*8..tr*8+7

__global__ __launch_bounds__(256) void sage_fused_k(
    const float* __restrict__ agg, float* __restrict__ h,
    const float* __restrict__ Wl, const float* __restrict__ bl,
    const float* __restrict__ Wr, const float* __restrict__ g,
    const float* __restrict__ bln, int N) {
    __shared__ float As[64][32];
    __shared__ float Ws[32][128];
    int tid = threadIdx.x;
    int tc = tid & 31, tr = tid >> 5;
    int m0 = blockIdx.x * 64;

    float acc[8][4];
#pragma unroll
    for (int r = 0; r < 8; r++)
#pragma unroll
        for (int c = 0; c < 4; c++) acc[r][c] = 0.0f;

    for (int kb = 0; kb < 8; kb++) {
        const float* Asrc = (kb < 4) ? agg : h;
        const float* Wsrc = (kb < 4) ? Wl : Wr;
        int kc0 = (kb & 3) * 32;
        __syncthreads();
        // A tile: 64 rows x 32 k  (512 float4 slots, 2 per thread)
#pragma unroll
        for (int i = 0; i < 2; i++) {
            int s = i * 256 + tid;
            int row = s >> 3, q = s & 7;
            float4 v = make_float4(0.f, 0.f, 0.f, 0.f);
            int grow = m0 + row;
            if (grow < N) v = *(const float4*)(Asrc + (size_t)grow * HH + kc0 + q * 4);
            *(float4*)(&As[row][q * 4]) = v;
        }
        // W tile: 32 k x 128 cols (1024 float4 slots, 4 per thread)
#pragma unroll
        for (int i = 0; i < 4; i++) {
            int s = i * 256 + tid;
            int k = s >> 5, qc = s & 31;
            *(float4*)(&Ws[k][qc * 4]) =
                *(const float4*)(Wsrc + (size_t)(kc0 + k) * HH + qc * 4);
        }
        __syncthreads();
#pragma unroll
        for (int k = 0; k < 32; k += 2) {
            float4 w0 = *(const float4*)(&Ws[k][tc * 4]);
            float4 w1 = *(const float4*)(&Ws[k + 1][tc * 4]);
#pragma unroll
            for (int r = 0; r < 8; r++) {
                float2 a = *(const float2*)(&As[tr * 8 + r][k]);
                acc[r][0] = fmaf(a.x, w0.x, fmaf(a.y, w1.x, acc[r][0]));
                acc[r][1] = fmaf(a.x, w0.y, fmaf(a.y, w1.y, acc[r][1]));
                acc[r][2] = fmaf(a.x, w0.z, fmaf(a.y, w1.z, acc[r][2]));
                acc[r][3] = fmaf(a.x, w0.w, fmaf(a.y, w1.w, acc[r][3]));
            }
        }
    }

    // epilogue: bias + LayerNorm + relu + residual, in place on h
    float4 bias = *(const float4*)(bl + tc * 4);
    float4 gg = *(const float4*)(g + tc * 4);
    float4 bb = *(const float4*)(bln + tc * 4);
#pragma unroll
    for (int r = 0; r < 8; r++) {
        float v0 = acc[r][0] + bias.x;
        float v1 = acc[r][1] + bias.y;
        float v2 = acc[r][2] + bias.z;
        float v3 = acc[r][3] + bias.w;
        float s = v0 + v1 + v2 + v3;
        float q = v0 * v0 + v1 * v1 + v2 * v2 + v3 * v3;
#pragma unroll
        for (int m = 1; m < 32; m <<= 1) {
            s += __shfl_xor(s, m);
            q += __shfl_xor(q, m);
        }
        float mean = s * (1.0f / 128.0f);
        float var = q * (1.0f / 128.0f) - mean * mean;
        float rstd = rsqrtf(fmaxf(var, 0.0f) + 1e-5f);
        int row = m0 + tr * 8 + r;
        if (row < N) {
            float4 old = *(float4*)(h + (size_t)row * HH + tc * 4);
            old.x += fmaxf((v0 - mean) * rstd * gg.x + bb.x, 0.0f);
            old.y += fmaxf((v1 - mean) * rstd * gg.y + bb.y, 0.0f);
            old.z += fmaxf((v2 - mean) * rstd * gg.z + bb.z, 0.0f);
            old.w += fmaxf((v3 - mean) * rstd * gg.w + bb.w, 0.0f);
            *(float4*)(h + (size_t)row * HH + tc * 4) = old;
        }
    }
}

// ---------------- pooling: per-graph mean + max (batch is sorted; h >= 0) ----------------

__global__ __launch_bounds__(128) void pool_k(
    const float* __restrict__ h, const int* __restrict__ batch,
    float* __restrict__ psum, int* __restrict__ pmax, int* __restrict__ pcnt, int N) {
    int j = threadIdx.x;
    int n0 = blockIdx.x * 256;
    int cur = -1, run = 0;
    float s = 0.0f, m = 0.0f;
    for (int t = 0; t < 256; t++) {
        int n = n0 + t;
        if (n >= N) break;
        int b = batch[n];
        if (b != cur) {
            if (cur >= 0) {
                atomicAdd(&psum[cur * HH + j], s);
                atomicMax(&pmax[cur * HH + j], __float_as_int(m));
                if (j == 0) atomicAdd(&pcnt[cur], run);
            }
            cur = b; s = 0.0f; m = 0.0f; run = 0;
        }
        float v = h[(size_t)n * HH + j];
        s += v;
        m = fmaxf(m, v);
        run++;
    }
    if (cur >= 0) {
        atomicAdd(&psum[cur * HH + j], s);
        atomicMax(&pmax[cur * HH + j], __float_as_int(m));
        if (j == 0) atomicAdd(&pcnt[cur], run);
    }
}

// ---------------- head: trackster MLP + concat + LN + classifier ----------------

__global__ __launch_bounds__(128) void head_k(
    const float* __restrict__ psum, const float* __restrict__ pmax,
    const int* __restrict__ pcnt, const float* __restrict__ ts,
    const float* __restrict__ tsW1, const float* __restrict__ tsb1,
    const float* __restrict__ tslng, const float* __restrict__ tslnb,
    const float* __restrict__ tsW2, const float* __restrict__ tsb2,
    const float* __restrict__ clng, const float* __restrict__ clnb,
    const float* __restrict__ cW1, const float* __restrict__ cb1,
    const float* __restrict__ cW2, const float* __restrict__ cb2,
    float* __restrict__ out) {
    int b = blockIdx.x;
    int t = threadIdx.x;
    __shared__ float feat[320];
    __shared__ float tn[64];
    __shared__ float zz[128];
    __shared__ float ps[2], pq[2];

    // trackster layer 1 + LN + relu (threads 0..63 == wave 0)
    if (t < 64) {
        float v = tsb1[t];
#pragma unroll
        for (int k = 0; k < 3; k++) v = fmaf(ts[b * 3 + k], tsW1[k * 64 + t], v);
        float s = v, q = v * v;
#pragma unroll
        for (int m = 1; m < 64; m <<= 1) {
            s += __shfl_xor(s, m);
            q += __shfl_xor(q, m);
        }
        float mean = s * (1.0f / 64.0f);
        float var = q * (1.0f / 64.0f) - mean * mean;
        float rstd = rsqrtf(fmaxf(var, 0.0f) + 1e-5f);
        tn[t] = fmaxf((v - mean) * rstd * tslng[t] + tslnb[t], 0.0f);
    }
    __syncthreads();
    if (t < 64) {
        float v = tsb2[t];
        for (int k = 0; k < 64; k++) v = fmaf(tn[k], tsW2[k * 64 + t], v);
        feat[256 + t] = v;
    }
    float cntf = (float)(pcnt[b] > 1 ? pcnt[b] : 1);
    feat[t] = psum[b * HH + t] / cntf;
    feat[128 + t] = pmax[b * HH + t];
    __syncthreads();

    // LN over 320
    float s = 0.0f, q = 0.0f;
    for (int i = t; i < 320; i += 128) {
        float v = feat[i];
        s += v;
        q += v * v;
    }
#pragma unroll
    for (int m = 1; m < 64; m <<= 1) {
        s += __shfl_xor(s, m);
        q += __shfl_xor(q, m);
    }
    if ((t & 63) == 0) { ps[t >> 6] = s; pq[t >> 6] = q; }
    __syncthreads();
    float S = ps[0] + ps[1], Q = pq[0] + pq[1];
    float mean = S * (1.0f / 320.0f);
    float var = Q * (1.0f / 320.0f) - mean * mean;
    float rstd = rsqrtf(fmaxf(var, 0.0f) + 1e-5f);
    for (int i = t; i < 320; i += 128)
        feat[i] = (feat[i] - mean) * rstd * clng[i] + clnb[i];
    __syncthreads();

    // z = relu(featn @ cW1 + cb1)
    {
        float v = cb1[t];
        for (int k = 0; k < 320; k++) v = fmaf(feat[k], cW1[k * HH + t], v);
        zz[t] = fmaxf(v, 0.0f);
    }
    __syncthreads();
    if (t < 8) {
        float v = cb2[t];
        for (int k = 0; k < 128; k++) v = fmaf(zz[k], cW2[k * 8 + t], v);
        out[b * 8 + t] = v;
    }
}

// ---------------- launcher ----------------

extern "C" void kernel_launch(void* const* d_in, const int* in_sizes, int n_in,
                              void* d_out, int out_size, void* d_ws, size_t ws_size,
                              hipStream_t stream) {
    const int N = in_sizes[0] / 4;
    const int E = in_sizes[1] / 2;
    const int B = in_sizes[3] / 3;

    const float* x    = (const float*)d_in[0];
    const int*   ei   = (const int*)d_in[1];
    const int*   srcv = ei;
    const int*   dstv = ei + E;
    const int*   batch = (const int*)d_in[2];
    const float* ts   = (const float*)d_in[3];
    const float* encW = (const float*)d_in[4];
    const float* encb = (const float*)d_in[5];
    const float* sageWl = (const float*)d_in[6];
    const float* sagebl = (const float*)d_in[7];
    const float* sageWr = (const float*)d_in[8];
    const float* lng  = (const float*)d_in[9];
    const float* lnb  = (const float*)d_in[10];
    const float* tsW1 = (const float*)d_in[11];
    const float* tsb1 = (const float*)d_in[12];
    const float* tslng = (const float*)d_in[13];
    const float* tslnb = (const float*)d_in[14];
    const float* tsW2 = (const float*)d_in[15];
    const float* tsb2 = (const float*)d_in[16];
    const float* clng = (const float*)d_in[17];
    const float* clnb = (const float*)d_in[18];
    const float* cW1  = (const float*)d_in[19];
    const float* cb1  = (const float*)d_in[20];
    const float* cW2  = (const float*)d_in[21];
    const float* cb2  = (const float*)d_in[22];
    float* out = (float*)d_out;

    char* w = (char*)d_ws;
    size_t off = 0;
    auto take = [&](size_t bytes) -> void* {
        void* p = w + off;
        off = (off + bytes + 255) & ~(size_t)255;
        return p;
    };
    float* h    = (float*)take((size_t)N * HH * 4);
    float* agg  = (float*)take((size_t)N * HH * 4);
    int*   csr  = (int*)take((size_t)E * 4);
    int*   cnt  = (int*)take((size_t)N * 4);
    int*   offs = (int*)take((size_t)(N + 1) * 4);
    int*   cursor = (int*)take((size_t)N * 4);
    float* invd = (float*)take((size_t)N * 4);
    int*   bsums = (int*)take((size_t)((N + 255) / 256) * 4);
    float* psum = (float*)take((size_t)B * HH * 4);
    int*   pmax = (int*)take((size_t)B * HH * 4);
    int*   pcnt = (int*)take((size_t)B * 4);

    hipMemsetAsync(cnt, 0, (size_t)N * 4, stream);
    hipMemsetAsync(psum, 0, (size_t)B * HH * 4, stream);
    hipMemsetAsync(pmax, 0, (size_t)B * HH * 4, stream);
    hipMemsetAsync(pcnt, 0, (size_t)B * 4, stream);

    int EB = (E + 255) / 256;
    int NB = (N + 255) / 256;
    count_k<<<EB, 256, 0, stream>>>(dstv, cnt, E);
    scan1<<<NB, 256, 0, stream>>>(cnt, offs, bsums, N);
    scan2<<<1, 1024, 0, stream>>>(bsums, NB);
    scan3<<<NB, 256, 0, stream>>>(cnt, offs, bsums, cursor, invd, N, E);
    scatter_k<<<EB, 256, 0, stream>>>(srcv, dstv, cursor, csr, E);

    encoder_k<<<(N + 1) / 2, 256, 0, stream>>>(x, encW, encb, h, N);

    for (int l = 0; l < 3; l++) {
        aggregate_k<<<(N + 1) / 2, 256, 0, stream>>>(h, offs, csr, invd, agg, N);
        sage_fused_k<<<(N + 63) / 64, 256, 0, stream>>>(
            agg, h, sageWl + (size_t)l * HH * HH, sagebl + (size_t)l * HH,
            sageWr + (size_t)l * HH * HH, lng + (size_t)l * HH, lnb + (size_t)l * HH, N);
    }

    pool_k<<<(N + 255) / 256, 128, 0, stream>>>(h, batch, psum, pmax, pcnt, N);
    head_k<<<B, 128, 0, stream>>>(psum, (const float*)pmax, pcnt, ts,
                                  tsW1, tsb1, tslng, tslnb, tsW2, tsb2,
                                  clng, clnb, cW1, cb1, cW2, cb2, out);
}

// Round 2
// 588.683 us; speedup vs baseline: 1.8471x; 1.8471x over previous
//
#include <hip/hip_runtime.h>
#include <hip/hip_bf16.h>

#define HH 128   // hidden dim

typedef __attribute__((ext_vector_type(8))) short short8;   // bf16x8 MFMA frag (4 VGPR)
typedef __attribute__((ext_vector_type(4))) float floatx4;  // MFMA acc frag

__device__ __forceinline__ ushort f2bf(float f) {
    uint u = __float_as_uint(f);
    uint r = (u + 0x7FFFu + ((u >> 16) & 1u)) >> 16;
    return (ushort)r;
}
__device__ __forceinline__ float bflo(uint p) { return __uint_as_float(p << 16); }
__device__ __forceinline__ float bfhi(uint p) { return __uint_as_float(p & 0xFFFF0000u); }
__device__ __forceinline__ uint packbf(float a, float b) {
    return (uint)f2bf(a) | ((uint)f2bf(b) << 16);
}

// ---------------- CSR build ----------------

__global__ void count_k(const int* __restrict__ dst, int* __restrict__ cnt, int E) {
    int e = blockIdx.x * 256 + threadIdx.x;
    if (e < E) atomicAdd(&cnt[dst[e]], 1);
}

__global__ void scan1(const int* __restrict__ cnt, int* __restrict__ loc,
                      int* __restrict__ bsums, int N) {
    __shared__ int s[256];
    int i = blockIdx.x * 256 + threadIdx.x;
    int v = (i < N) ? cnt[i] : 0;
    s[threadIdx.x] = v;
    __syncthreads();
    for (int o = 1; o < 256; o <<= 1) {
        int t = (threadIdx.x >= o) ? s[threadIdx.x - o] : 0;
        __syncthreads();
        s[threadIdx.x] += t;
        __syncthreads();
    }
    if (i < N) loc[i] = s[threadIdx.x] - v;
    if (threadIdx.x == 255) bsums[blockIdx.x] = s[255];
}

__global__ void scan2(int* __restrict__ bs, int NB) {
    __shared__ int s[1024];
    int t = threadIdx.x;
    int v = (t < NB) ? bs[t] : 0;
    s[t] = v;
    __syncthreads();
    for (int o = 1; o < 1024; o <<= 1) {
        int tv = (t >= o) ? s[t - o] : 0;
        __syncthreads();
        s[t] += tv;
        __syncthreads();
    }
    if (t < NB) bs[t] = s[t] - v;
}

__global__ void scan3(const int* __restrict__ cnt, int* __restrict__ offs,
                      const int* __restrict__ bs, int* __restrict__ cursor,
                      float* __restrict__ invd, int N, int E) {
    int i = blockIdx.x * 256 + threadIdx.x;
    if (i < N) {
        int o = offs[i] + bs[blockIdx.x];
        offs[i] = o;
        cursor[i] = o;
        int d = cnt[i];
        invd[i] = 1.0f / (float)(d > 1 ? d : 1);
    }
    if (i == 0) offs[N] = E;
}

__global__ void scatter_k(const int* __restrict__ src, const int* __restrict__ dst,
                          int* __restrict__ cursor, int* __restrict__ csr, int E) {
    int e = blockIdx.x * 256 + threadIdx.x;
    if (e < E) {
        int d = dst[e];
        int p = atomicAdd(&cursor[d], 1);
        csr[p] = src[e];
    }
}

// ---------------- weight packing: [Wl;Wr] -> bf16 MFMA B-frag layout ----------------
// Bp[layer][((ks*8+ct)*64+lane)*8+j] = B[k][n], k=ks*32+(lane>>4)*8+j, n=ct*16+(lane&15)
// k<128 -> Wl[k][n], k>=128 -> Wr[k-128][n]

__global__ __launch_bounds__(256) void prep_w_k(
    const float* __restrict__ Wl, const float* __restrict__ Wr, ushort* __restrict__ Bp) {
    int gid = blockIdx.x * 256 + threadIdx.x;    // 3*32768 total
    int layer = gid >> 15;
    int r = gid & 32767;
    int j = r & 7;
    int lane = (r >> 3) & 63;
    int ct = (r >> 9) & 7;
    int ks = r >> 12;
    int k = ks * 32 + (lane >> 4) * 8 + j;
    int n = ct * 16 + (lane & 15);
    float v = (k < HH) ? Wl[(size_t)layer * HH * HH + k * HH + n]
                       : Wr[(size_t)layer * HH * HH + (k - HH) * HH + n];
    Bp[gid] = f2bf(v);
}

// ---------------- node encoder: h = relu(x @ encW + encb), fp32 + bf16 mirror ----------------

__global__ __launch_bounds__(256) void encoder_k(
    const float* __restrict__ x, const float* __restrict__ W,
    const float* __restrict__ b, float* __restrict__ h, uint* __restrict__ hb, int N) {
    int n = blockIdx.x * 4 + (threadIdx.x >> 6);
    int j = threadIdx.x & 63;       // cols 2j, 2j+1
    if (n >= N) return;
    float4 xv = *(const float4*)(x + (size_t)n * 4);
    float v0 = b[2 * j], v1 = b[2 * j + 1];
    v0 = fmaf(xv.x, W[0 * HH + 2 * j], v0); v1 = fmaf(xv.x, W[0 * HH + 2 * j + 1], v1);
    v0 = fmaf(xv.y, W[1 * HH + 2 * j], v0); v1 = fmaf(xv.y, W[1 * HH + 2 * j + 1], v1);
    v0 = fmaf(xv.z, W[2 * HH + 2 * j], v0); v1 = fmaf(xv.z, W[2 * HH + 2 * j + 1], v1);
    v0 = fmaf(xv.w, W[3 * HH + 2 * j], v0); v1 = fmaf(xv.w, W[3 * HH + 2 * j + 1], v1);
    v0 = fmaxf(v0, 0.0f); v1 = fmaxf(v1, 0.0f);
    h[(size_t)n * HH + 2 * j] = v0;
    h[(size_t)n * HH + 2 * j + 1] = v1;
    hb[(size_t)n * 64 + j] = packbf(v0, v1);
}

// ---------------- mean aggregation over in-neighbors (bf16 gather, 4x unroll) ----------------

__global__ __launch_bounds__(256) void aggregate_k(
    const uint* __restrict__ hb, const int* __restrict__ offs,
    const int* __restrict__ csr, const float* __restrict__ invd,
    uint* __restrict__ aggb, int N) {
    int n = blockIdx.x * 4 + (threadIdx.x >> 6);
    int j = threadIdx.x & 63;
    if (n >= N) return;
    int s = offs[n], e = offs[n + 1];
    float a0 = 0.0f, a1 = 0.0f;
    int i = s;
    for (; i + 4 <= e; i += 4) {
        int u0 = csr[i], u1 = csr[i + 1], u2 = csr[i + 2], u3 = csr[i + 3];
        uint p0 = hb[(size_t)u0 * 64 + j];
        uint p1 = hb[(size_t)u1 * 64 + j];
        uint p2 = hb[(size_t)u2 * 64 + j];
        uint p3 = hb[(size_t)u3 * 64 + j];
        a0 += (bflo(p0) + bflo(p1)) + (bflo(p2) + bflo(p3));
        a1 += (bfhi(p0) + bfhi(p1)) + (bfhi(p2) + bfhi(p3));
    }
    for (; i < e; i++) {
        uint p = hb[(size_t)csr[i] * 64 + j];
        a0 += bflo(p);
        a1 += bfhi(p);
    }
    float iv = invd[n];
    aggb[(size_t)n * 64 + j] = packbf(a0 * iv, a1 * iv);
}

// ---------------- fused SAGE layer via MFMA bf16 ----------------
// block = 256 thr = 4 waves; wave covers rows m0..m0+31 (2 row-tiles of 16), all 128 cols.
// A frag: A[m=lane&15][k=quad*8+j] direct from row-major bf16 agg/h.
// C/D: col=lane&15, row=quad*4+reg.

__global__ __launch_bounds__(256) void sage_mfma_k(
    const ushort* __restrict__ aggb, float* __restrict__ h, ushort* __restrict__ hb,
    const ushort* __restrict__ Bp, const float* __restrict__ bl,
    const float* __restrict__ g, const float* __restrict__ bln, int N) {
    int wave = threadIdx.x >> 6;
    int lane = threadIdx.x & 63;
    int m0 = blockIdx.x * 128 + wave * 32;

    floatx4 acc[2][8];
#pragma unroll
    for (int rt = 0; rt < 2; rt++)
#pragma unroll
        for (int ct = 0; ct < 8; ct++) acc[rt][ct] = (floatx4)0.0f;

    int am = lane & 15, aq = lane >> 4;
#pragma unroll
    for (int ks = 0; ks < 8; ks++) {
        const ushort* Asrc = (ks < 4) ? aggb : (const ushort*)hb;
        int kc = (ks & 3) * 32 + aq * 8;
        short8 a[2];
#pragma unroll
        for (int rt = 0; rt < 2; rt++) {
            int row = m0 + rt * 16 + am;
            row = row < N ? row : N - 1;
            a[rt] = *(const short8*)(Asrc + (size_t)row * HH + kc);
        }
#pragma unroll
        for (int ct = 0; ct < 8; ct++) {
            short8 b = *(const short8*)(Bp + (((size_t)(ks * 8 + ct)) * 64 + lane) * 8);
            acc[0][ct] = __builtin_amdgcn_mfma_f32_16x16x32_bf16(a[0], b, acc[0][ct], 0, 0, 0);
            acc[1][ct] = __builtin_amdgcn_mfma_f32_16x16x32_bf16(a[1], b, acc[1][ct], 0, 0, 0);
        }
    }

    // epilogue: bias + LN(128) + relu + residual (fp32 master + bf16 mirror)
    int g4 = lane >> 4, cl = lane & 15;
    float bias[8], gam[8], bet[8];
#pragma unroll
    for (int ct = 0; ct < 8; ct++) {
        bias[ct] = bl[ct * 16 + cl];
        gam[ct] = g[ct * 16 + cl];
        bet[ct] = bln[ct * 16 + cl];
    }
#pragma unroll
    for (int rt = 0; rt < 2; rt++) {
        float sr[4], qr[4];
#pragma unroll
        for (int reg = 0; reg < 4; reg++) {
            float s = 0.0f, q = 0.0f;
#pragma unroll
            for (int ct = 0; ct < 8; ct++) {
                float v = acc[rt][ct][reg] + bias[ct];
                s += v;
                q += v * v;
            }
#pragma unroll
            for (int m = 1; m < 16; m <<= 1) {
                s += __shfl_xor(s, m);
                q += __shfl_xor(q, m);
            }
            sr[reg] = s;
            qr[reg] = q;
        }
#pragma unroll
        for (int reg = 0; reg < 4; reg++) {
            int row = m0 + rt * 16 + g4 * 4 + reg;
            if (row < N) {
                float mean = sr[reg] * (1.0f / 128.0f);
                float var = qr[reg] * (1.0f / 128.0f) - mean * mean;
                float rstd = rsqrtf(fmaxf(var, 0.0f) + 1e-5f);
#pragma unroll
                for (int ct = 0; ct < 8; ct++) {
                    float v = acc[rt][ct][reg] + bias[ct];
                    float r = fmaxf((v - mean) * rstd * gam[ct] + bet[ct], 0.0f);
                    size_t idx = (size_t)row * HH + ct * 16 + cl;
                    float nv = h[idx] + r;
                    h[idx] = nv;
                    hb[idx] = f2bf(nv);
                }
            }
        }
    }
}

// ---------------- pooling: per-graph mean + max (batch sorted; h >= 0) ----------------

__global__ __launch_bounds__(128) void pool_k(
    const float* __restrict__ h, const int* __restrict__ batch,
    float* __restrict__ psum, int* __restrict__ pmax, int* __restrict__ pcnt, int N) {
    int j = threadIdx.x;
    int n0 = blockIdx.x * 256;
    int cur = -1, run = 0;
    float s = 0.0f, m = 0.0f;
    for (int t = 0; t < 256; t++) {
        int n = n0 + t;
        if (n >= N) break;
        int b = batch[n];
        if (b != cur) {
            if (cur >= 0) {
                atomicAdd(&psum[cur * HH + j], s);
                atomicMax(&pmax[cur * HH + j], __float_as_int(m));
                if (j == 0) atomicAdd(&pcnt[cur], run);
            }
            cur = b; s = 0.0f; m = 0.0f; run = 0;
        }
        float v = h[(size_t)n * HH + j];
        s += v;
        m = fmaxf(m, v);
        run++;
    }
    if (cur >= 0) {
        atomicAdd(&psum[cur * HH + j], s);
        atomicMax(&pmax[cur * HH + j], __float_as_int(m));
        if (j == 0) atomicAdd(&pcnt[cur], run);
    }
}

// ---------------- head: trackster MLP + concat + LN + classifier ----------------

__global__ __launch_bounds__(128) void head_k(
    const float* __restrict__ psum, const float* __restrict__ pmax,
    const int* __restrict__ pcnt, const float* __restrict__ ts,
    const float* __restrict__ tsW1, const float* __restrict__ tsb1,
    const float* __restrict__ tslng, const float* __restrict__ tslnb,
    const float* __restrict__ tsW2, const float* __restrict__ tsb2,
    const float* __restrict__ clng, const float* __restrict__ clnb,
    const float* __restrict__ cW1, const float* __restrict__ cb1,
    const float* __restrict__ cW2, const float* __restrict__ cb2,
    float* __restrict__ out) {
    int b = blockIdx.x;
    int t = threadIdx.x;
    __shared__ float feat[320];
    __shared__ float tn[64];
    __shared__ float zz[128];
    __shared__ float ps[2], pq[2];

    if (t < 64) {
        float v = tsb1[t];
#pragma unroll
        for (int k = 0; k < 3; k++) v = fmaf(ts[b * 3 + k], tsW1[k * 64 + t], v);
        float s = v, q = v * v;
#pragma unroll
        for (int m = 1; m < 64; m <<= 1) {
            s += __shfl_xor(s, m);
            q += __shfl_xor(q, m);
        }
        float mean = s * (1.0f / 64.0f);
        float var = q * (1.0f / 64.0f) - mean * mean;
        float rstd = rsqrtf(fmaxf(var, 0.0f) + 1e-5f);
        tn[t] = fmaxf((v - mean) * rstd * tslng[t] + tslnb[t], 0.0f);
    }
    __syncthreads();
    if (t < 64) {
        float v = tsb2[t];
        for (int k = 0; k < 64; k++) v = fmaf(tn[k], tsW2[k * 64 + t], v);
        feat[256 + t] = v;
    }
    float cntf = (float)(pcnt[b] > 1 ? pcnt[b] : 1);
    feat[t] = psum[b * HH + t] / cntf;
    feat[128 + t] = pmax[b * HH + t];
    __syncthreads();

    float s = 0.0f, q = 0.0f;
    for (int i = t; i < 320; i += 128) {
        float v = feat[i];
        s += v;
        q += v * v;
    }
#pragma unroll
    for (int m = 1; m < 64; m <<= 1) {
        s += __shfl_xor(s, m);
        q += __shfl_xor(q, m);
    }
    if ((t & 63) == 0) { ps[t >> 6] = s; pq[t >> 6] = q; }
    __syncthreads();
    float S = ps[0] + ps[1], Q = pq[0] + pq[1];
    float mean = S * (1.0f / 320.0f);
    float var = Q * (1.0f / 320.0f) - mean * mean;
    float rstd = rsqrtf(fmaxf(var, 0.0f) + 1e-5f);
    for (int i = t; i < 320; i += 128)
        feat[i] = (feat[i] - mean) * rstd * clng[i] + clnb[i];
    __syncthreads();

    {
        float v = cb1[t];
        for (int k = 0; k < 320; k++) v = fmaf(feat[k], cW1[k * HH + t], v);
        zz[t] = fmaxf(v, 0.0f);
    }
    __syncthreads();
    if (t < 8) {
        float v = cb2[t];
        for (int k = 0; k < 128; k++) v = fmaf(zz[k], cW2[k * 8 + t], v);
        out[b * 8 + t] = v;
    }
}

// ---------------- launcher ----------------

extern "C" void kernel_launch(void* const* d_in, const int* in_sizes, int n_in,
                              void* d_out, int out_size, void* d_ws, size_t ws_size,
                              hipStream_t stream) {
    const int N = in_sizes[0] / 4;
    const int E = in_sizes[1] / 2;
    const int B = in_sizes[3] / 3;

    const float* x    = (const float*)d_in[0];
    const int*   ei   = (const int*)d_in[1];
    const int*   srcv = ei;
    const int*   dstv = ei + E;
    const int*   batch = (const int*)d_in[2];
    const float* ts   = (const float*)d_in[3];
    const float* encW = (const float*)d_in[4];
    const float* encb = (const float*)d_in[5];
    const float* sageWl = (const float*)d_in[6];
    const float* sagebl = (const float*)d_in[7];
    const float* sageWr = (const float*)d_in[8];
    const float* lng  = (const float*)d_in[9];
    const float* lnb  = (const float*)d_in[10];
    const float* tsW1 = (const float*)d_in[11];
    const float* tsb1 = (const float*)d_in[12];
    const float* tslng = (const float*)d_in[13];
    const float* tslnb = (const float*)d_in[14];
    const float* tsW2 = (const float*)d_in[15];
    const float* tsb2 = (const float*)d_in[16];
    const float* clng = (const float*)d_in[17];
    const float* clnb = (const float*)d_in[18];
    const float* cW1  = (const float*)d_in[19];
    const float* cb1  = (const float*)d_in[20];
    const float* cW2  = (const float*)d_in[21];
    const float* cb2  = (const float*)d_in[22];
    float* out = (float*)d_out;

    char* w = (char*)d_ws;
    size_t off = 0;
    auto take = [&](size_t bytes) -> void* {
        void* p = w + off;
        off = (off + bytes + 255) & ~(size_t)255;
        return p;
    };
    float* h    = (float*)take((size_t)N * HH * 4);   // fp32 residual master
    uint*  hb   = (uint*)take((size_t)N * HH * 2);    // bf16 mirror
    uint*  aggb = (uint*)take((size_t)N * HH * 2);    // bf16 aggregate
    ushort* Bp  = (ushort*)take((size_t)3 * HH * 2 * HH * 2); // packed weights
    int*   csr  = (int*)take((size_t)E * 4);
    int*   cnt  = (int*)take((size_t)N * 4);
    int*   offs = (int*)take((size_t)(N + 1) * 4);
    int*   cursor = (int*)take((size_t)N * 4);
    float* invd = (float*)take((size_t)N * 4);
    int*   bsums = (int*)take((size_t)((N + 255) / 256) * 4);
    float* psum = (float*)take((size_t)B * HH * 4);
    int*   pmax = (int*)take((size_t)B * HH * 4);
    int*   pcnt = (int*)take((size_t)B * 4);

    hipMemsetAsync(cnt, 0, (size_t)N * 4, stream);
    hipMemsetAsync(psum, 0, (size_t)B * HH * 4, stream);
    hipMemsetAsync(pmax, 0, (size_t)B * HH * 4, stream);
    hipMemsetAsync(pcnt, 0, (size_t)B * 4, stream);

    int EB = (E + 255) / 256;
    int NB = (N + 255) / 256;
    count_k<<<EB, 256, 0, stream>>>(dstv, cnt, E);
    scan1<<<NB, 256, 0, stream>>>(cnt, offs, bsums, N);
    scan2<<<1, 1024, 0, stream>>>(bsums, NB);
    scan3<<<NB, 256, 0, stream>>>(cnt, offs, bsums, cursor, invd, N, E);
    scatter_k<<<EB, 256, 0, stream>>>(srcv, dstv, cursor, csr, E);

    prep_w_k<<<384, 256, 0, stream>>>(sageWl, sageWr, Bp);
    encoder_k<<<(N + 3) / 4, 256, 0, stream>>>(x, encW, encb, h, hb, N);

    for (int l = 0; l < 3; l++) {
        aggregate_k<<<(N + 3) / 4, 256, 0, stream>>>(hb, offs, csr, invd, aggb, N);
        sage_mfma_k<<<(N + 127) / 128, 256, 0, stream>>>(
            (const ushort*)aggb, h, (ushort*)hb, Bp + (size_t)l * 32768,
            sagebl + (size_t)l * HH, lng + (size_t)l * HH, lnb + (size_t)l * HH, N);
    }

    pool_k<<<(N + 255) / 256, 128, 0, stream>>>(h, batch, psum, pmax, pcnt, N);
    head_k<<<B, 128, 0, stream>>>(psum, (const float*)pmax, pcnt, ts,
                                  tsW1, tsb1, tslng, tslnb, tsW2, tsb2,
                                  clng, clnb, cW1, cb1, cW2, cb2, out);
}

// Round 3
// 572.951 us; speedup vs baseline: 1.8978x; 1.0275x over previous
//
#include <hip/hip_runtime.h>
#include <hip/hip_bf16.h>

#define HH 128   // hidden dim

typedef __attribute__((ext_vector_type(8))) short short8;   // bf16x8 MFMA frag (4 VGPR)
typedef __attribute__((ext_vector_type(4))) float floatx4;  // MFMA acc frag

__device__ __forceinline__ ushort f2bf(float f) {
    uint u = __float_as_uint(f);
    uint r = (u + 0x7FFFu + ((u >> 16) & 1u)) >> 16;
    return (ushort)r;
}
__device__ __forceinline__ float bflo(uint p) { return __uint_as_float(p << 16); }
__device__ __forceinline__ float bfhi(uint p) { return __uint_as_float(p & 0xFFFF0000u); }
__device__ __forceinline__ uint packbf(float a, float b) {
    return (uint)f2bf(a) | ((uint)f2bf(b) << 16);
}

// ---------------- CSR build ----------------

__global__ void count_k(const int* __restrict__ dst, int* __restrict__ cnt, int E) {
    int e = blockIdx.x * 256 + threadIdx.x;
    if (e < E) atomicAdd(&cnt[dst[e]], 1);
}

__global__ void scan1(const int* __restrict__ cnt, int* __restrict__ loc,
                      int* __restrict__ bsums, int N) {
    __shared__ int s[256];
    int i = blockIdx.x * 256 + threadIdx.x;
    int v = (i < N) ? cnt[i] : 0;
    s[threadIdx.x] = v;
    __syncthreads();
    for (int o = 1; o < 256; o <<= 1) {
        int t = (threadIdx.x >= o) ? s[threadIdx.x - o] : 0;
        __syncthreads();
        s[threadIdx.x] += t;
        __syncthreads();
    }
    if (i < N) loc[i] = s[threadIdx.x] - v;
    if (threadIdx.x == 255) bsums[blockIdx.x] = s[255];
}

__global__ void scan2(int* __restrict__ bs, int NB) {
    __shared__ int s[1024];
    int t = threadIdx.x;
    int v = (t < NB) ? bs[t] : 0;
    s[t] = v;
    __syncthreads();
    for (int o = 1; o < 1024; o <<= 1) {
        int tv = (t >= o) ? s[t - o] : 0;
        __syncthreads();
        s[t] += tv;
        __syncthreads();
    }
    if (t < NB) bs[t] = s[t] - v;
}

__global__ void scan3(const int* __restrict__ cnt, int* __restrict__ offs,
                      const int* __restrict__ bs, int* __restrict__ cursor,
                      float* __restrict__ invd, int N, int E) {
    int i = blockIdx.x * 256 + threadIdx.x;
    if (i < N) {
        int o = offs[i] + bs[blockIdx.x];
        offs[i] = o;
        cursor[i] = o;
        int d = cnt[i];
        invd[i] = 1.0f / (float)(d > 1 ? d : 1);
    }
    if (i == 0) offs[N] = E;
}

__global__ void scatter_k(const int* __restrict__ src, const int* __restrict__ dst,
                          int* __restrict__ cursor, int* __restrict__ csr, int E) {
    int e = blockIdx.x * 256 + threadIdx.x;
    if (e < E) {
        int d = dst[e];
        int p = atomicAdd(&cursor[d], 1);
        csr[p] = src[e];
    }
}

// ---------------- weight packing: [Wl;Wr] -> bf16 MFMA B-frag layout ----------------

__global__ __launch_bounds__(256) void prep_w_k(
    const float* __restrict__ Wl, const float* __restrict__ Wr, ushort* __restrict__ Bp) {
    int gid = blockIdx.x * 256 + threadIdx.x;    // 3*32768 total
    int layer = gid >> 15;
    int r = gid & 32767;
    int j = r & 7;
    int lane = (r >> 3) & 63;
    int ct = (r >> 9) & 7;
    int ks = r >> 12;
    int k = ks * 32 + (lane >> 4) * 8 + j;
    int n = ct * 16 + (lane & 15);
    float v = (k < HH) ? Wl[(size_t)layer * HH * HH + k * HH + n]
                       : Wr[(size_t)layer * HH * HH + (k - HH) * HH + n];
    Bp[gid] = f2bf(v);
}

// ---------------- node encoder: h = relu(x @ encW + encb), fp32 + bf16 mirror ----------------

__global__ __launch_bounds__(256) void encoder_k(
    const float* __restrict__ x, const float* __restrict__ W,
    const float* __restrict__ b, float* __restrict__ h, uint* __restrict__ hb, int N) {
    int n = blockIdx.x * 4 + (threadIdx.x >> 6);
    int j = threadIdx.x & 63;       // cols 2j, 2j+1
    if (n >= N) return;
    float4 xv = *(const float4*)(x + (size_t)n * 4);
    float v0 = b[2 * j], v1 = b[2 * j + 1];
    v0 = fmaf(xv.x, W[0 * HH + 2 * j], v0); v1 = fmaf(xv.x, W[0 * HH + 2 * j + 1], v1);
    v0 = fmaf(xv.y, W[1 * HH + 2 * j], v0); v1 = fmaf(xv.y, W[1 * HH + 2 * j + 1], v1);
    v0 = fmaf(xv.z, W[2 * HH + 2 * j], v0); v1 = fmaf(xv.z, W[2 * HH + 2 * j + 1], v1);
    v0 = fmaf(xv.w, W[3 * HH + 2 * j], v0); v1 = fmaf(xv.w, W[3 * HH + 2 * j + 1], v1);
    v0 = fmaxf(v0, 0.0f); v1 = fmaxf(v1, 0.0f);
    h[(size_t)n * HH + 2 * j] = v0;
    h[(size_t)n * HH + 2 * j + 1] = v1;
    hb[(size_t)n * 64 + j] = packbf(v0, v1);
}

// ---------------- mean aggregation over in-neighbors (bf16 gather, uint2, 4x unroll) ----------------

__global__ __launch_bounds__(256) void aggregate_k(
    const uint* __restrict__ hb, const int* __restrict__ offs,
    const int* __restrict__ csr, const float* __restrict__ invd,
    uint* __restrict__ aggb, int N) {
    int n = blockIdx.x * 8 + (threadIdx.x >> 5);
    int j = threadIdx.x & 31;     // uint2 -> cols 4j..4j+3
    if (n >= N) return;
    const uint2* hb2 = (const uint2*)hb;
    int s = offs[n], e = offs[n + 1];
    float a0 = 0.0f, a1 = 0.0f, a2 = 0.0f, a3 = 0.0f;
    int i = s;
    for (; i + 4 <= e; i += 4) {
        int u0 = csr[i], u1 = csr[i + 1], u2 = csr[i + 2], u3 = csr[i + 3];
        uint2 p0 = hb2[(size_t)u0 * 32 + j];
        uint2 p1 = hb2[(size_t)u1 * 32 + j];
        uint2 p2 = hb2[(size_t)u2 * 32 + j];
        uint2 p3 = hb2[(size_t)u3 * 32 + j];
        a0 += (bflo(p0.x) + bflo(p1.x)) + (bflo(p2.x) + bflo(p3.x));
        a1 += (bfhi(p0.x) + bfhi(p1.x)) + (bfhi(p2.x) + bfhi(p3.x));
        a2 += (bflo(p0.y) + bflo(p1.y)) + (bflo(p2.y) + bflo(p3.y));
        a3 += (bfhi(p0.y) + bfhi(p1.y)) + (bfhi(p2.y) + bfhi(p3.y));
    }
    for (; i < e; i++) {
        uint2 p = hb2[(size_t)csr[i] * 32 + j];
        a0 += bflo(p.x);
        a1 += bfhi(p.x);
        a2 += bflo(p.y);
        a3 += bfhi(p.y);
    }
    float iv = invd[n];
    uint2 o;
    o.x = packbf(a0 * iv, a1 * iv);
    o.y = packbf(a2 * iv, a3 * iv);
    ((uint2*)aggb)[(size_t)n * 32 + j] = o;
}

// ---------------- fused SAGE layer via MFMA bf16 ----------------
// block = 256 thr = 4 waves; wave covers rows m0..m0+31 (2 row-tiles of 16), all 128 cols.
// A frag: A[m=lane&15][k=quad*8+j] direct from row-major bf16 agg/h.
// C/D: col=lane&15, row=quad*4+reg.

__global__ __launch_bounds__(256) void sage_mfma_k(
    const ushort* __restrict__ aggb, float* __restrict__ h, ushort* __restrict__ hb,
    const ushort* __restrict__ Bp, const float* __restrict__ bl,
    const float* __restrict__ g, const float* __restrict__ bln, int N) {
    int wave = threadIdx.x >> 6;
    int lane = threadIdx.x & 63;
    int m0 = blockIdx.x * 128 + wave * 32;

    floatx4 acc[2][8];
#pragma unroll
    for (int rt = 0; rt < 2; rt++)
#pragma unroll
        for (int ct = 0; ct < 8; ct++) acc[rt][ct] = (floatx4)0.0f;

    int am = lane & 15, aq = lane >> 4;
#pragma unroll
    for (int ks = 0; ks < 8; ks++) {
        const ushort* Asrc = (ks < 4) ? aggb : (const ushort*)hb;
        int kc = (ks & 3) * 32 + aq * 8;
        short8 a[2];
#pragma unroll
        for (int rt = 0; rt < 2; rt++) {
            int row = m0 + rt * 16 + am;
            row = row < N ? row : N - 1;
            a[rt] = *(const short8*)(Asrc + (size_t)row * HH + kc);
        }
#pragma unroll
        for (int ct = 0; ct < 8; ct++) {
            short8 b = *(const short8*)(Bp + (((size_t)(ks * 8 + ct)) * 64 + lane) * 8);
            acc[0][ct] = __builtin_amdgcn_mfma_f32_16x16x32_bf16(a[0], b, acc[0][ct], 0, 0, 0);
            acc[1][ct] = __builtin_amdgcn_mfma_f32_16x16x32_bf16(a[1], b, acc[1][ct], 0, 0, 0);
        }
    }

    // epilogue: bias + LN(128) + relu + residual (fp32 master + bf16 mirror)
    int g4 = lane >> 4, cl = lane & 15;
    float bias[8], gam[8], bet[8];
#pragma unroll
    for (int ct = 0; ct < 8; ct++) {
        bias[ct] = bl[ct * 16 + cl];
        gam[ct] = g[ct * 16 + cl];
        bet[ct] = bln[ct * 16 + cl];
    }
#pragma unroll
    for (int rt = 0; rt < 2; rt++) {
        float sr[4], qr[4];
#pragma unroll
        for (int reg = 0; reg < 4; reg++) {
            float s = 0.0f, q = 0.0f;
#pragma unroll
            for (int ct = 0; ct < 8; ct++) {
                float v = acc[rt][ct][reg] + bias[ct];
                s += v;
                q += v * v;
            }
#pragma unroll
            for (int m = 1; m < 16; m <<= 1) {
                s += __shfl_xor(s, m);
                q += __shfl_xor(q, m);
            }
            sr[reg] = s;
            qr[reg] = q;
        }
#pragma unroll
        for (int reg = 0; reg < 4; reg++) {
            int row = m0 + rt * 16 + g4 * 4 + reg;
            if (row < N) {
                float mean = sr[reg] * (1.0f / 128.0f);
                float var = qr[reg] * (1.0f / 128.0f) - mean * mean;
                float rstd = rsqrtf(fmaxf(var, 0.0f) + 1e-5f);
#pragma unroll
                for (int ct = 0; ct < 8; ct++) {
                    float v = acc[rt][ct][reg] + bias[ct];
                    float r = fmaxf((v - mean) * rstd * gam[ct] + bet[ct], 0.0f);
                    size_t idx = (size_t)row * HH + ct * 16 + cl;
                    float nv = h[idx] + r;
                    h[idx] = nv;
                    hb[idx] = f2bf(nv);
                }
            }
        }
    }
}

// ---------------- pooling v2: chunked, register-accumulated, bf16 reads ----------------
// block = 256 thr: 8 row-slots x 32 lanes (uint2 = 4 cols each); chunk = 64 rows.
// batch sorted; within a thread rows strictly increase -> run/flush logic valid. h >= 0.

__global__ __launch_bounds__(256) void pool_k(
    const uint* __restrict__ hb, const int* __restrict__ batch,
    float* __restrict__ psum, int* __restrict__ pmax, int* __restrict__ pcnt, int N) {
    int lane = threadIdx.x & 31;   // cols 4*lane .. 4*lane+3
    int slot = threadIdx.x >> 5;   // 8 row slots
    int base = blockIdx.x * 64;
    const uint2* hb2 = (const uint2*)hb;
    int cur = -1, run = 0;
    float s0 = 0, s1 = 0, s2 = 0, s3 = 0, m0 = 0, m1 = 0, m2 = 0, m3 = 0;
#pragma unroll
    for (int i = 0; i < 8; i++) {
        int n = base + i * 8 + slot;
        if (n >= N) break;
        int b = batch[n];
        if (b != cur) {
            if (cur >= 0) {
                int cb = cur * HH + lane * 4;
                atomicAdd(&psum[cb + 0], s0);
                atomicAdd(&psum[cb + 1], s1);
                atomicAdd(&psum[cb + 2], s2);
                atomicAdd(&psum[cb + 3], s3);
                atomicMax(&pmax[cb + 0], __float_as_int(m0));
                atomicMax(&pmax[cb + 1], __float_as_int(m1));
                atomicMax(&pmax[cb + 2], __float_as_int(m2));
                atomicMax(&pmax[cb + 3], __float_as_int(m3));
                if (lane == 0) atomicAdd(&pcnt[cur], run);
            }
            cur = b;
            s0 = s1 = s2 = s3 = 0.0f;
            m0 = m1 = m2 = m3 = 0.0f;
            run = 0;
        }
        uint2 p = hb2[(size_t)n * 32 + lane];
        float v0 = bflo(p.x), v1 = bfhi(p.x), v2 = bflo(p.y), v3 = bfhi(p.y);
        s0 += v0; s1 += v1; s2 += v2; s3 += v3;
        m0 = fmaxf(m0, v0); m1 = fmaxf(m1, v1);
        m2 = fmaxf(m2, v2); m3 = fmaxf(m3, v3);
        run++;
    }
    if (cur >= 0) {
        int cb = cur * HH + lane * 4;
        atomicAdd(&psum[cb + 0], s0);
        atomicAdd(&psum[cb + 1], s1);
        atomicAdd(&psum[cb + 2], s2);
        atomicAdd(&psum[cb + 3], s3);
        atomicMax(&pmax[cb + 0], __float_as_int(m0));
        atomicMax(&pmax[cb + 1], __float_as_int(m1));
        atomicMax(&pmax[cb + 2], __float_as_int(m2));
        atomicMax(&pmax[cb + 3], __float_as_int(m3));
        if (lane == 0) atomicAdd(&pcnt[cur], run);
    }
}

// ---------------- head: trackster MLP + concat + LN + classifier ----------------

__global__ __launch_bounds__(128) void head_k(
    const float* __restrict__ psum, const float* __restrict__ pmax,
    const int* __restrict__ pcnt, const float* __restrict__ ts,
    const float* __restrict__ tsW1, const float* __restrict__ tsb1,
    const float* __restrict__ tslng, const float* __restrict__ tslnb,
    const float* __restrict__ tsW2, const float* __restrict__ tsb2,
    const float* __restrict__ clng, const float* __restrict__ clnb,
    const float* __restrict__ cW1, const float* __restrict__ cb1,
    const float* __restrict__ cW2, const float* __restrict__ cb2,
    float* __restrict__ out) {
    int b = blockIdx.x;
    int t = threadIdx.x;
    __shared__ float feat[320];
    __shared__ float tn[64];
    __shared__ float zz[128];
    __shared__ float ps[2], pq[2];

    if (t < 64) {
        float v = tsb1[t];
#pragma unroll
        for (int k = 0; k < 3; k++) v = fmaf(ts[b * 3 + k], tsW1[k * 64 + t], v);
        float s = v, q = v * v;
#pragma unroll
        for (int m = 1; m < 64; m <<= 1) {
            s += __shfl_xor(s, m);
            q += __shfl_xor(q, m);
        }
        float mean = s * (1.0f / 64.0f);
        float var = q * (1.0f / 64.0f) - mean * mean;
        float rstd = rsqrtf(fmaxf(var, 0.0f) + 1e-5f);
        tn[t] = fmaxf((v - mean) * rstd * tslng[t] + tslnb[t], 0.0f);
    }
    __syncthreads();
    if (t < 64) {
        float v = tsb2[t];
        for (int k = 0; k < 64; k++) v = fmaf(tn[k], tsW2[k * 64 + t], v);
        feat[256 + t] = v;
    }
    float cntf = (float)(pcnt[b] > 1 ? pcnt[b] : 1);
    feat[t] = psum[b * HH + t] / cntf;
    feat[128 + t] = pmax[b * HH + t];
    __syncthreads();

    float s = 0.0f, q = 0.0f;
    for (int i = t; i < 320; i += 128) {
        float v = feat[i];
        s += v;
        q += v * v;
    }
#pragma unroll
    for (int m = 1; m < 64; m <<= 1) {
        s += __shfl_xor(s, m);
        q += __shfl_xor(q, m);
    }
    if ((t & 63) == 0) { ps[t >> 6] = s; pq[t >> 6] = q; }
    __syncthreads();
    float S = ps[0] + ps[1], Q = pq[0] + pq[1];
    float mean = S * (1.0f / 320.0f);
    float var = Q * (1.0f / 320.0f) - mean * mean;
    float rstd = rsqrtf(fmaxf(var, 0.0f) + 1e-5f);
    for (int i = t; i < 320; i += 128)
        feat[i] = (feat[i] - mean) * rstd * clng[i] + clnb[i];
    __syncthreads();

    {
        float v = cb1[t];
        for (int k = 0; k < 320; k++) v = fmaf(feat[k], cW1[k * HH + t], v);
        zz[t] = fmaxf(v, 0.0f);
    }
    __syncthreads();
    if (t < 8) {
        float v = cb2[t];
        for (int k = 0; k < 128; k++) v = fmaf(zz[k], cW2[k * 8 + t], v);
        out[b * 8 + t] = v;
    }
}

// ---------------- launcher ----------------

extern "C" void kernel_launch(void* const* d_in, const int* in_sizes, int n_in,
                              void* d_out, int out_size, void* d_ws, size_t ws_size,
                              hipStream_t stream) {
    const int N = in_sizes[0] / 4;
    const int E = in_sizes[1] / 2;
    const int B = in_sizes[3] / 3;

    const float* x    = (const float*)d_in[0];
    const int*   ei   = (const int*)d_in[1];
    const int*   srcv = ei;
    const int*   dstv = ei + E;
    const int*   batch = (const int*)d_in[2];
    const float* ts   = (const float*)d_in[3];
    const float* encW = (const float*)d_in[4];
    const float* encb = (const float*)d_in[5];
    const float* sageWl = (const float*)d_in[6];
    const float* sagebl = (const float*)d_in[7];
    const float* sageWr = (const float*)d_in[8];
    const float* lng  = (const float*)d_in[9];
    const float* lnb  = (const float*)d_in[10];
    const float* tsW1 = (const float*)d_in[11];
    const float* tsb1 = (const float*)d_in[12];
    const float* tslng = (const float*)d_in[13];
    const float* tslnb = (const float*)d_in[14];
    const float* tsW2 = (const float*)d_in[15];
    const float* tsb2 = (const float*)d_in[16];
    const float* clng = (const float*)d_in[17];
    const float* clnb = (const float*)d_in[18];
    const float* cW1  = (const float*)d_in[19];
    const float* cb1  = (const float*)d_in[20];
    const float* cW2  = (const float*)d_in[21];
    const float* cb2  = (const float*)d_in[22];
    float* out = (float*)d_out;

    char* w = (char*)d_ws;
    size_t off = 0;
    auto take = [&](size_t bytes) -> void* {
        void* p = w + off;
        off = (off + bytes + 255) & ~(size_t)255;
        return p;
    };
    float* h    = (float*)take((size_t)N * HH * 4);   // fp32 residual master
    uint*  hb   = (uint*)take((size_t)N * HH * 2);    // bf16 mirror
    uint*  aggb = (uint*)take((size_t)N * HH * 2);    // bf16 aggregate
    ushort* Bp  = (ushort*)take((size_t)3 * HH * 2 * HH * 2); // packed weights
    int*   csr  = (int*)take((size_t)E * 4);
    int*   cnt  = (int*)take((size_t)N * 4);
    int*   offs = (int*)take((size_t)(N + 1) * 4);
    int*   cursor = (int*)take((size_t)N * 4);
    float* invd = (float*)take((size_t)N * 4);
    int*   bsums = (int*)take((size_t)((N + 255) / 256) * 4);
    float* psum = (float*)take((size_t)B * HH * 4);
    int*   pmax = (int*)take((size_t)B * HH * 4);
    int*   pcnt = (int*)take((size_t)B * 4);

    hipMemsetAsync(cnt, 0, (size_t)N * 4, stream);
    hipMemsetAsync(psum, 0, (size_t)B * HH * 4, stream);
    hipMemsetAsync(pmax, 0, (size_t)B * HH * 4, stream);
    hipMemsetAsync(pcnt, 0, (size_t)B * 4, stream);

    int EB = (E + 255) / 256;
    int NB = (N + 255) / 256;
    count_k<<<EB, 256, 0, stream>>>(dstv, cnt, E);
    scan1<<<NB, 256, 0, stream>>>(cnt, offs, bsums, N);
    scan2<<<1, 1024, 0, stream>>>(bsums, NB);
    scan3<<<NB, 256, 0, stream>>>(cnt, offs, bsums, cursor, invd, N, E);
    scatter_k<<<EB, 256, 0, stream>>>(srcv, dstv, cursor, csr, E);

    prep_w_k<<<384, 256, 0, stream>>>(sageWl, sageWr, Bp);
    encoder_k<<<(N + 3) / 4, 256, 0, stream>>>(x, encW, encb, h, hb, N);

    for (int l = 0; l < 3; l++) {
        aggregate_k<<<(N + 7) / 8, 256, 0, stream>>>(hb, offs, csr, invd, aggb, N);
        sage_mfma_k<<<(N + 127) / 128, 256, 0, stream>>>(
            (const ushort*)aggb, h, (ushort*)hb, Bp + (size_t)l * 32768,
            sagebl + (size_t)l * HH, lng + (size_t)l * HH, lnb + (size_t)l * HH, N);
    }

    pool_k<<<(N + 63) / 64, 256, 0, stream>>>(hb, batch, psum, pmax, pcnt, N);
    head_k<<<B, 128, 0, stream>>>(psum, (const float*)pmax, pcnt, ts,
                                  tsW1, tsb1, tslng, tslnb, tsW2, tsb2,
                                  clng, clnb, cW1, cb1, cW2, cb2, out);
}

// Round 4
// 480.146 us; speedup vs baseline: 2.2646x; 1.1933x over previous
//
#include <hip/hip_runtime.h>
#include <hip/hip_bf16.h>

#define HH 128   // hidden dim

typedef __attribute__((ext_vector_type(8))) short short8;   // bf16x8 MFMA frag (4 VGPR)
typedef __attribute__((ext_vector_type(4))) float floatx4;  // MFMA acc frag

__device__ __forceinline__ ushort f2bf(float f) {
    uint u = __float_as_uint(f);
    uint r = (u + 0x7FFFu + ((u >> 16) & 1u)) >> 16;
    return (ushort)r;
}
__device__ __forceinline__ float bflo(uint p) { return __uint_as_float(p << 16); }
__device__ __forceinline__ float bfhi(uint p) { return __uint_as_float(p & 0xFFFF0000u); }
__device__ __forceinline__ uint packbf(float a, float b) {
    return (uint)f2bf(a) | ((uint)f2bf(b) << 16);
}

// ---------------- CSR build ----------------

__global__ void count_k(const int* __restrict__ dst, int* __restrict__ cnt, int E) {
    int e = blockIdx.x * 256 + threadIdx.x;
    if (e < E) atomicAdd(&cnt[dst[e]], 1);
}

__global__ void scan1(const int* __restrict__ cnt, int* __restrict__ loc,
                      int* __restrict__ bsums, int N) {
    __shared__ int s[256];
    int i = blockIdx.x * 256 + threadIdx.x;
    int v = (i < N) ? cnt[i] : 0;
    s[threadIdx.x] = v;
    __syncthreads();
    for (int o = 1; o < 256; o <<= 1) {
        int t = (threadIdx.x >= o) ? s[threadIdx.x - o] : 0;
        __syncthreads();
        s[threadIdx.x] += t;
        __syncthreads();
    }
    if (i < N) loc[i] = s[threadIdx.x] - v;
    if (threadIdx.x == 255) bsums[blockIdx.x] = s[255];
}

__global__ void scan2(int* __restrict__ bs, int NB) {
    __shared__ int s[1024];
    int t = threadIdx.x;
    int v = (t < NB) ? bs[t] : 0;
    s[t] = v;
    __syncthreads();
    for (int o = 1; o < 1024; o <<= 1) {
        int tv = (t >= o) ? s[t - o] : 0;
        __syncthreads();
        s[t] += tv;
        __syncthreads();
    }
    if (t < NB) bs[t] = s[t] - v;
}

__global__ void scan3(const int* __restrict__ cnt, int* __restrict__ offs,
                      const int* __restrict__ bs, int* __restrict__ cursor,
                      float* __restrict__ invd, int N, int E) {
    int i = blockIdx.x * 256 + threadIdx.x;
    if (i < N) {
        int o = offs[i] + bs[blockIdx.x];
        offs[i] = o;
        cursor[i] = o;
        int d = cnt[i];
        invd[i] = 1.0f / (float)(d > 1 ? d : 1);
    }
    if (i == 0) offs[N] = E;
}

__global__ void scatter_k(const int* __restrict__ src, const int* __restrict__ dst,
                          int* __restrict__ cursor, int* __restrict__ csr, int E) {
    int e = blockIdx.x * 256 + threadIdx.x;
    if (e < E) {
        int d = dst[e];
        int p = atomicAdd(&cursor[d], 1);
        csr[p] = src[e];
    }
}

// ---------------- weight packing: [Wl;Wr] -> bf16 MFMA B-frag layout ----------------

__global__ __launch_bounds__(256) void prep_w_k(
    const float* __restrict__ Wl, const float* __restrict__ Wr, ushort* __restrict__ Bp) {
    int gid = blockIdx.x * 256 + threadIdx.x;    // 3*32768 total
    int layer = gid >> 15;
    int r = gid & 32767;
    int j = r & 7;
    int lane = (r >> 3) & 63;
    int ct = (r >> 9) & 7;
    int ks = r >> 12;
    int k = ks * 32 + (lane >> 4) * 8 + j;
    int n = ct * 16 + (lane & 15);
    float v = (k < HH) ? Wl[(size_t)layer * HH * HH + k * HH + n]
                       : Wr[(size_t)layer * HH * HH + (k - HH) * HH + n];
    Bp[gid] = f2bf(v);
}

// ---------------- node encoder: h = relu(x @ encW + encb), fp32 + bf16 mirror ----------------

__global__ __launch_bounds__(256) void encoder_k(
    const float* __restrict__ x, const float* __restrict__ W,
    const float* __restrict__ b, float* __restrict__ h, uint* __restrict__ hb, int N) {
    int n = blockIdx.x * 4 + (threadIdx.x >> 6);
    int j = threadIdx.x & 63;       // cols 2j, 2j+1
    if (n >= N) return;
    float4 xv = *(const float4*)(x + (size_t)n * 4);
    float v0 = b[2 * j], v1 = b[2 * j + 1];
    v0 = fmaf(xv.x, W[0 * HH + 2 * j], v0); v1 = fmaf(xv.x, W[0 * HH + 2 * j + 1], v1);
    v0 = fmaf(xv.y, W[1 * HH + 2 * j], v0); v1 = fmaf(xv.y, W[1 * HH + 2 * j + 1], v1);
    v0 = fmaf(xv.z, W[2 * HH + 2 * j], v0); v1 = fmaf(xv.z, W[2 * HH + 2 * j + 1], v1);
    v0 = fmaf(xv.w, W[3 * HH + 2 * j], v0); v1 = fmaf(xv.w, W[3 * HH + 2 * j + 1], v1);
    v0 = fmaxf(v0, 0.0f); v1 = fmaxf(v1, 0.0f);
    h[(size_t)n * HH + 2 * j] = v0;
    h[(size_t)n * HH + 2 * j + 1] = v1;
    hb[(size_t)n * 64 + j] = packbf(v0, v1);
}

// ---------------- mean aggregation over in-neighbors (bf16 gather, uint4, 4x unroll) ----------------
// 16 lanes per node (uint4 = 8 cols each), 16 nodes per 256-block.

__global__ __launch_bounds__(256) void aggregate_k(
    const uint* __restrict__ hb, const int* __restrict__ offs,
    const int* __restrict__ csr, const float* __restrict__ invd,
    uint* __restrict__ aggb, int N) {
    int n = blockIdx.x * 16 + (threadIdx.x >> 4);
    int j = threadIdx.x & 15;     // uint4 -> cols 8j..8j+7
    if (n >= N) return;
    const uint4* hb4 = (const uint4*)hb;
    int s = offs[n], e = offs[n + 1];
    float a0 = 0, a1 = 0, a2 = 0, a3 = 0, a4 = 0, a5 = 0, a6 = 0, a7 = 0;
    int i = s;
    for (; i + 4 <= e; i += 4) {
        int u0 = csr[i], u1 = csr[i + 1], u2 = csr[i + 2], u3 = csr[i + 3];
        uint4 p0 = hb4[(size_t)u0 * 16 + j];
        uint4 p1 = hb4[(size_t)u1 * 16 + j];
        uint4 p2 = hb4[(size_t)u2 * 16 + j];
        uint4 p3 = hb4[(size_t)u3 * 16 + j];
        a0 += (bflo(p0.x) + bflo(p1.x)) + (bflo(p2.x) + bflo(p3.x));
        a1 += (bfhi(p0.x) + bfhi(p1.x)) + (bfhi(p2.x) + bfhi(p3.x));
        a2 += (bflo(p0.y) + bflo(p1.y)) + (bflo(p2.y) + bflo(p3.y));
        a3 += (bfhi(p0.y) + bfhi(p1.y)) + (bfhi(p2.y) + bfhi(p3.y));
        a4 += (bflo(p0.z) + bflo(p1.z)) + (bflo(p2.z) + bflo(p3.z));
        a5 += (bfhi(p0.z) + bfhi(p1.z)) + (bfhi(p2.z) + bfhi(p3.z));
        a6 += (bflo(p0.w) + bflo(p1.w)) + (bflo(p2.w) + bflo(p3.w));
        a7 += (bfhi(p0.w) + bfhi(p1.w)) + (bfhi(p2.w) + bfhi(p3.w));
    }
    for (; i < e; i++) {
        uint4 p = hb4[(size_t)csr[i] * 16 + j];
        a0 += bflo(p.x); a1 += bfhi(p.x);
        a2 += bflo(p.y); a3 += bfhi(p.y);
        a4 += bflo(p.z); a5 += bfhi(p.z);
        a6 += bflo(p.w); a7 += bfhi(p.w);
    }
    float iv = invd[n];
    uint4 o;
    o.x = packbf(a0 * iv, a1 * iv);
    o.y = packbf(a2 * iv, a3 * iv);
    o.z = packbf(a4 * iv, a5 * iv);
    o.w = packbf(a6 * iv, a7 * iv);
    ((uint4*)aggb)[(size_t)n * 16 + j] = o;
}

// ---------------- fused SAGE layer via MFMA bf16 ----------------

__global__ __launch_bounds__(256) void sage_mfma_k(
    const ushort* __restrict__ aggb, float* __restrict__ h, ushort* __restrict__ hb,
    const ushort* __restrict__ Bp, const float* __restrict__ bl,
    const float* __restrict__ g, const float* __restrict__ bln, int N) {
    int wave = threadIdx.x >> 6;
    int lane = threadIdx.x & 63;
    int m0 = blockIdx.x * 128 + wave * 32;

    floatx4 acc[2][8];
#pragma unroll
    for (int rt = 0; rt < 2; rt++)
#pragma unroll
        for (int ct = 0; ct < 8; ct++) acc[rt][ct] = (floatx4)0.0f;

    int am = lane & 15, aq = lane >> 4;
#pragma unroll
    for (int ks = 0; ks < 8; ks++) {
        const ushort* Asrc = (ks < 4) ? aggb : (const ushort*)hb;
        int kc = (ks & 3) * 32 + aq * 8;
        short8 a[2];
#pragma unroll
        for (int rt = 0; rt < 2; rt++) {
            int row = m0 + rt * 16 + am;
            row = row < N ? row : N - 1;
            a[rt] = *(const short8*)(Asrc + (size_t)row * HH + kc);
        }
#pragma unroll
        for (int ct = 0; ct < 8; ct++) {
            short8 b = *(const short8*)(Bp + (((size_t)(ks * 8 + ct)) * 64 + lane) * 8);
            acc[0][ct] = __builtin_amdgcn_mfma_f32_16x16x32_bf16(a[0], b, acc[0][ct], 0, 0, 0);
            acc[1][ct] = __builtin_amdgcn_mfma_f32_16x16x32_bf16(a[1], b, acc[1][ct], 0, 0, 0);
        }
    }

    // epilogue: bias + LN(128) + relu + residual (fp32 master + bf16 mirror)
    int g4 = lane >> 4, cl = lane & 15;
    float bias[8], gam[8], bet[8];
#pragma unroll
    for (int ct = 0; ct < 8; ct++) {
        bias[ct] = bl[ct * 16 + cl];
        gam[ct] = g[ct * 16 + cl];
        bet[ct] = bln[ct * 16 + cl];
    }
#pragma unroll
    for (int rt = 0; rt < 2; rt++) {
        float sr[4], qr[4];
#pragma unroll
        for (int reg = 0; reg < 4; reg++) {
            float s = 0.0f, q = 0.0f;
#pragma unroll
            for (int ct = 0; ct < 8; ct++) {
                float v = acc[rt][ct][reg] + bias[ct];
                s += v;
                q += v * v;
            }
#pragma unroll
            for (int m = 1; m < 16; m <<= 1) {
                s += __shfl_xor(s, m);
                q += __shfl_xor(q, m);
            }
            sr[reg] = s;
            qr[reg] = q;
        }
#pragma unroll
        for (int reg = 0; reg < 4; reg++) {
            int row = m0 + rt * 16 + g4 * 4 + reg;
            if (row < N) {
                float mean = sr[reg] * (1.0f / 128.0f);
                float var = qr[reg] * (1.0f / 128.0f) - mean * mean;
                float rstd = rsqrtf(fmaxf(var, 0.0f) + 1e-5f);
#pragma unroll
                for (int ct = 0; ct < 8; ct++) {
                    float v = acc[rt][ct][reg] + bias[ct];
                    float r = fmaxf((v - mean) * rstd * gam[ct] + bet[ct], 0.0f);
                    size_t idx = (size_t)row * HH + ct * 16 + cl;
                    float nv = h[idx] + r;
                    h[idx] = nv;
                    hb[idx] = f2bf(nv);
                }
            }
        }
    }
}

// ---------------- pooling v3: 256-row chunks, LDS block reduction, few atomics ----------------
// 8 row-slots x 32 lanes (uint2 = 4 cols). Fast path: whole chunk in one graph
// (batch sorted -> endpoints equal implies uniform) -> register acc + LDS reduce +
// 1 atomic per column per block. Slow path (<=B-1 blocks): per-thread run/flush.

__global__ __launch_bounds__(256) void pool_k(
    const uint* __restrict__ hb, const int* __restrict__ batch,
    float* __restrict__ psum, int* __restrict__ pmax, int* __restrict__ pcnt, int N) {
    __shared__ float ls[8][32][4];
    __shared__ float lm[8][32][4];
    int tid = threadIdx.x;
    int lane = tid & 31;   // cols 4*lane .. 4*lane+3
    int slot = tid >> 5;   // 8 row slots
    int n0 = blockIdx.x * 256;
    int nlast = n0 + 255 < N - 1 ? n0 + 255 : N - 1;
    const uint2* hb2 = (const uint2*)hb;
    int b0 = batch[n0];

    if (batch[nlast] == b0) {
        // ---- fast path ----
        float s0 = 0, s1 = 0, s2 = 0, s3 = 0, m0 = 0, m1 = 0, m2 = 0, m3 = 0;
        for (int i = 0; i < 32; i++) {
            int n = n0 + i * 8 + slot;
            if (n < N) {
                uint2 p = hb2[(size_t)n * 32 + lane];
                float v0 = bflo(p.x), v1 = bfhi(p.x), v2 = bflo(p.y), v3 = bfhi(p.y);
                s0 += v0; s1 += v1; s2 += v2; s3 += v3;
                m0 = fmaxf(m0, v0); m1 = fmaxf(m1, v1);
                m2 = fmaxf(m2, v2); m3 = fmaxf(m3, v3);
            }
        }
        ls[slot][lane][0] = s0; ls[slot][lane][1] = s1;
        ls[slot][lane][2] = s2; ls[slot][lane][3] = s3;
        lm[slot][lane][0] = m0; lm[slot][lane][1] = m1;
        lm[slot][lane][2] = m2; lm[slot][lane][3] = m3;
        __syncthreads();
        if (tid < 128) {          // column = tid = 4*(tid>>2) + (tid&3)
            int ln = tid >> 2, c = tid & 3;
            float s = 0.0f, m = 0.0f;
#pragma unroll
            for (int sl = 0; sl < 8; sl++) {
                s += ls[sl][ln][c];
                m = fmaxf(m, lm[sl][ln][c]);
            }
            atomicAdd(&psum[b0 * HH + tid], s);
            atomicMax(&pmax[b0 * HH + tid], __float_as_int(m));
        }
        if (tid == 0) {
            int rows = (N - n0 < 256) ? (N - n0) : 256;
            atomicAdd(&pcnt[b0], rows);
        }
    } else {
        // ---- slow path (graph boundary inside chunk) ----
        int cur = -1, run = 0;
        float s0 = 0, s1 = 0, s2 = 0, s3 = 0, m0 = 0, m1 = 0, m2 = 0, m3 = 0;
        for (int i = 0; i < 32; i++) {
            int n = n0 + i * 8 + slot;
            if (n >= N) break;
            int b = batch[n];
            if (b != cur) {
                if (cur >= 0) {
                    int cb = cur * HH + lane * 4;
                    atomicAdd(&psum[cb + 0], s0);
                    atomicAdd(&psum[cb + 1], s1);
                    atomicAdd(&psum[cb + 2], s2);
                    atomicAdd(&psum[cb + 3], s3);
                    atomicMax(&pmax[cb + 0], __float_as_int(m0));
                    atomicMax(&pmax[cb + 1], __float_as_int(m1));
                    atomicMax(&pmax[cb + 2], __float_as_int(m2));
                    atomicMax(&pmax[cb + 3], __float_as_int(m3));
                    if (lane == 0) atomicAdd(&pcnt[cur], run);
                }
                cur = b;
                s0 = s1 = s2 = s3 = 0.0f;
                m0 = m1 = m2 = m3 = 0.0f;
                run = 0;
            }
            uint2 p = hb2[(size_t)n * 32 + lane];
            float v0 = bflo(p.x), v1 = bfhi(p.x), v2 = bflo(p.y), v3 = bfhi(p.y);
            s0 += v0; s1 += v1; s2 += v2; s3 += v3;
            m0 = fmaxf(m0, v0); m1 = fmaxf(m1, v1);
            m2 = fmaxf(m2, v2); m3 = fmaxf(m3, v3);
            run++;
        }
        if (cur >= 0) {
            int cb = cur * HH + lane * 4;
            atomicAdd(&psum[cb + 0], s0);
            atomicAdd(&psum[cb + 1], s1);
            atomicAdd(&psum[cb + 2], s2);
            atomicAdd(&psum[cb + 3], s3);
            atomicMax(&pmax[cb + 0], __float_as_int(m0));
            atomicMax(&pmax[cb + 1], __float_as_int(m1));
            atomicMax(&pmax[cb + 2], __float_as_int(m2));
            atomicMax(&pmax[cb + 3], __float_as_int(m3));
            if (lane == 0) atomicAdd(&pcnt[cur], run);
        }
    }
}

// ---------------- head: trackster MLP + concat + LN + classifier ----------------

__global__ __launch_bounds__(128) void head_k(
    const float* __restrict__ psum, const float* __restrict__ pmax,
    const int* __restrict__ pcnt, const float* __restrict__ ts,
    const float* __restrict__ tsW1, const float* __restrict__ tsb1,
    const float* __restrict__ tslng, const float* __restrict__ tslnb,
    const float* __restrict__ tsW2, const float* __restrict__ tsb2,
    const float* __restrict__ clng, const float* __restrict__ clnb,
    const float* __restrict__ cW1, const float* __restrict__ cb1,
    const float* __restrict__ cW2, const float* __restrict__ cb2,
    float* __restrict__ out) {
    int b = blockIdx.x;
    int t = threadIdx.x;
    __shared__ float feat[320];
    __shared__ float tn[64];
    __shared__ float zz[128];
    __shared__ float ps[2], pq[2];

    if (t < 64) {
        float v = tsb1[t];
#pragma unroll
        for (int k = 0; k < 3; k++) v = fmaf(ts[b * 3 + k], tsW1[k * 64 + t], v);
        float s = v, q = v * v;
#pragma unroll
        for (int m = 1; m < 64; m <<= 1) {
            s += __shfl_xor(s, m);
            q += __shfl_xor(q, m);
        }
        float mean = s * (1.0f / 64.0f);
        float var = q * (1.0f / 64.0f) - mean * mean;
        float rstd = rsqrtf(fmaxf(var, 0.0f) + 1e-5f);
        tn[t] = fmaxf((v - mean) * rstd * tslng[t] + tslnb[t], 0.0f);
    }
    __syncthreads();
    if (t < 64) {
        float v = tsb2[t];
        for (int k = 0; k < 64; k++) v = fmaf(tn[k], tsW2[k * 64 + t], v);
        feat[256 + t] = v;
    }
    float cntf = (float)(pcnt[b] > 1 ? pcnt[b] : 1);
    feat[t] = psum[b * HH + t] / cntf;
    feat[128 + t] = pmax[b * HH + t];
    __syncthreads();

    float s = 0.0f, q = 0.0f;
    for (int i = t; i < 320; i += 128) {
        float v = feat[i];
        s += v;
        q += v * v;
    }
#pragma unroll
    for (int m = 1; m < 64; m <<= 1) {
        s += __shfl_xor(s, m);
        q += __shfl_xor(q, m);
    }
    if ((t & 63) == 0) { ps[t >> 6] = s; pq[t >> 6] = q; }
    __syncthreads();
    float S = ps[0] + ps[1], Q = pq[0] + pq[1];
    float mean = S * (1.0f / 320.0f);
    float var = Q * (1.0f / 320.0f) - mean * mean;
    float rstd = rsqrtf(fmaxf(var, 0.0f) + 1e-5f);
    for (int i = t; i < 320; i += 128)
        feat[i] = (feat[i] - mean) * rstd * clng[i] + clnb[i];
    __syncthreads();

    {
        float v = cb1[t];
        for (int k = 0; k < 320; k++) v = fmaf(feat[k], cW1[k * HH + t], v);
        zz[t] = fmaxf(v, 0.0f);
    }
    __syncthreads();
    if (t < 8) {
        float v = cb2[t];
        for (int k = 0; k < 128; k++) v = fmaf(zz[k], cW2[k * 8 + t], v);
        out[b * 8 + t] = v;
    }
}

// ---------------- launcher ----------------

extern "C" void kernel_launch(void* const* d_in, const int* in_sizes, int n_in,
                              void* d_out, int out_size, void* d_ws, size_t ws_size,
                              hipStream_t stream) {
    const int N = in_sizes[0] / 4;
    const int E = in_sizes[1] / 2;
    const int B = in_sizes[3] / 3;

    const float* x    = (const float*)d_in[0];
    const int*   ei   = (const int*)d_in[1];
    const int*   srcv = ei;
    const int*   dstv = ei + E;
    const int*   batch = (const int*)d_in[2];
    const float* ts   = (const float*)d_in[3];
    const float* encW = (const float*)d_in[4];
    const float* encb = (const float*)d_in[5];
    const float* sageWl = (const float*)d_in[6];
    const float* sagebl = (const float*)d_in[7];
    const float* sageWr = (const float*)d_in[8];
    const float* lng  = (const float*)d_in[9];
    const float* lnb  = (const float*)d_in[10];
    const float* tsW1 = (const float*)d_in[11];
    const float* tsb1 = (const float*)d_in[12];
    const float* tslng = (const float*)d_in[13];
    const float* tslnb = (const float*)d_in[14];
    const float* tsW2 = (const float*)d_in[15];
    const float* tsb2 = (const float*)d_in[16];
    const float* clng = (const float*)d_in[17];
    const float* clnb = (const float*)d_in[18];
    const float* cW1  = (const float*)d_in[19];
    const float* cb1  = (const float*)d_in[20];
    const float* cW2  = (const float*)d_in[21];
    const float* cb2  = (const float*)d_in[22];
    float* out = (float*)d_out;

    char* w = (char*)d_ws;
    size_t off = 0;
    auto take = [&](size_t bytes) -> void* {
        void* p = w + off;
        off = (off + bytes + 255) & ~(size_t)255;
        return p;
    };
    float* h    = (float*)take((size_t)N * HH * 4);   // fp32 residual master
    uint*  hb   = (uint*)take((size_t)N * HH * 2);    // bf16 mirror
    uint*  aggb = (uint*)take((size_t)N * HH * 2);    // bf16 aggregate
    ushort* Bp  = (ushort*)take((size_t)3 * HH * 2 * HH * 2); // packed weights
    int*   csr  = (int*)take((size_t)E * 4);
    int*   cnt  = (int*)take((size_t)N * 4);
    int*   offs = (int*)take((size_t)(N + 1) * 4);
    int*   cursor = (int*)take((size_t)N * 4);
    float* invd = (float*)take((size_t)N * 4);
    int*   bsums = (int*)take((size_t)((N + 255) / 256) * 4);
    float* psum = (float*)take((size_t)B * HH * 4);
    int*   pmax = (int*)take((size_t)B * HH * 4);
    int*   pcnt = (int*)take((size_t)B * 4);

    hipMemsetAsync(cnt, 0, (size_t)N * 4, stream);
    hipMemsetAsync(psum, 0, (size_t)B * HH * 4, stream);
    hipMemsetAsync(pmax, 0, (size_t)B * HH * 4, stream);
    hipMemsetAsync(pcnt, 0, (size_t)B * 4, stream);

    int EB = (E + 255) / 256;
    int NB = (N + 255) / 256;
    count_k<<<EB, 256, 0, stream>>>(dstv, cnt, E);
    scan1<<<NB, 256, 0, stream>>>(cnt, offs, bsums, N);
    scan2<<<1, 1024, 0, stream>>>(bsums, NB);
    scan3<<<NB, 256, 0, stream>>>(cnt, offs, bsums, cursor, invd, N, E);
    scatter_k<<<EB, 256, 0, stream>>>(srcv, dstv, cursor, csr, E);

    prep_w_k<<<384, 256, 0, stream>>>(sageWl, sageWr, Bp);
    encoder_k<<<(N + 3) / 4, 256, 0, stream>>>(x, encW, encb, h, hb, N);

    for (int l = 0; l < 3; l++) {
        aggregate_k<<<(N + 15) / 16, 256, 0, stream>>>(hb, offs, csr, invd, aggb, N);
        sage_mfma_k<<<(N + 127) / 128, 256, 0, stream>>>(
            (const ushort*)aggb, h, (ushort*)hb, Bp + (size_t)l * 32768,
            sagebl + (size_t)l * HH, lng + (size_t)l * HH, lnb + (size_t)l * HH, N);
    }

    pool_k<<<(N + 255) / 256, 256, 0, stream>>>(hb, batch, psum, pmax, pcnt, N);
    head_k<<<B, 128, 0, stream>>>(psum, (const float*)pmax, pcnt, ts,
                                  tsW1, tsb1, tslng, tslnb, tsW2, tsb2,
                                  clng, clnb, cW1, cb1, cW2, cb2, out);
}

// Round 5
// 422.966 us; speedup vs baseline: 2.5707x; 1.1352x over previous
//
#include <hip/hip_runtime.h>
#include <hip/hip_bf16.h>

#define HH 128      // hidden dim
#define BUK_SH 9    // 512 nodes per bucket
#define BUK 512
#define CAP 8192    // edge capacity per bucket (mean 4096, sigma ~64 -> 64-sigma margin)

typedef __attribute__((ext_vector_type(8))) short short8;   // bf16x8 MFMA frag (4 VGPR)
typedef __attribute__((ext_vector_type(4))) float floatx4;  // MFMA acc frag

__device__ __forceinline__ ushort f2bf(float f) {
    uint u = __float_as_uint(f);
    uint r = (u + 0x7FFFu + ((u >> 16) & 1u)) >> 16;
    return (ushort)r;
}
__device__ __forceinline__ float bflo(uint p) { return __uint_as_float(p << 16); }
__device__ __forceinline__ float bfhi(uint p) { return __uint_as_float(p & 0xFFFF0000u); }
__device__ __forceinline__ uint packbf(float a, float b) {
    return (uint)f2bf(a) | ((uint)f2bf(b) << 16);
}

// ---------------- CSR build, bucketed (write-amp-free) ----------------
// Phase 1: bin edges into 512-node buckets; packed u32 = (dst&511)<<17 | src.
// Assumes N <= 131072 (nbuk <= 256, src < 2^17).

__global__ __launch_bounds__(256) void bin_k(
    const int* __restrict__ src, const int* __restrict__ dst,
    int* __restrict__ gcur, uint* __restrict__ ebuf, int E) {
    __shared__ int hist[256];
    __shared__ int base[256];
    int tid = threadIdx.x;
    hist[tid] = 0;
    __syncthreads();
    int e0 = blockIdx.x * 2048;
    int d[8];
#pragma unroll
    for (int i = 0; i < 8; i++) {
        int e = e0 + i * 256 + tid;
        d[i] = (e < E) ? dst[e] : -1;
        if (d[i] >= 0) atomicAdd(&hist[d[i] >> BUK_SH], 1);
    }
    __syncthreads();
    if (hist[tid] > 0) base[tid] = atomicAdd(&gcur[tid], hist[tid]);
    hist[tid] = 0;
    __syncthreads();
#pragma unroll
    for (int i = 0; i < 8; i++) {
        if (d[i] >= 0) {
            int e = e0 + i * 256 + tid;
            int b = d[i] >> BUK_SH;
            int p = base[b] + atomicAdd(&hist[b], 1);
            if (p < CAP)
                ebuf[(size_t)b * CAP + p] = ((uint)(d[i] & (BUK - 1)) << 17) | (uint)src[e];
        }
    }
}

// Phase 2: exclusive scan of bucket counts (nbuk <= 256), 1 block.
__global__ void bscan_k(const int* __restrict__ gcur, int* __restrict__ bbase, int nbuk) {
    __shared__ int s[256];
    int t = threadIdx.x;
    int v = (t < nbuk) ? gcur[t] : 0;
    s[t] = v;
    __syncthreads();
    for (int o = 1; o < 256; o <<= 1) {
        int tv = (t >= o) ? s[t - o] : 0;
        __syncthreads();
        s[t] += tv;
        __syncthreads();
    }
    if (t < nbuk) bbase[t] = s[t] - v;
}

// Phase 3: per-bucket CSR segment built in LDS, streamed out coalesced.
__global__ __launch_bounds__(256) void build_k(
    const uint* __restrict__ ebuf, const int* __restrict__ gcur,
    const int* __restrict__ bbase, int* __restrict__ offs, float* __restrict__ invd,
    int* __restrict__ csr, int N, int nbuk) {
    __shared__ int ncnt[BUK];      // per-node count, later cursor
    __shared__ int npre[BUK];      // per-node exclusive prefix
    __shared__ int ss[256];
    __shared__ int csrbuf[CAP];
    int b = blockIdx.x, tid = threadIdx.x;
    int cnt = gcur[b]; if (cnt > CAP) cnt = CAP;
    int base = bbase[b];
    ncnt[tid] = 0; ncnt[tid + 256] = 0;
    __syncthreads();
    const uint* eb = ebuf + (size_t)b * CAP;
    for (int i = tid; i < cnt; i += 256) atomicAdd(&ncnt[eb[i] >> 17], 1);
    __syncthreads();
    // scan 512 counters with 256 threads: pair-sum then Hillis-Steele
    int a0 = ncnt[2 * tid], a1 = ncnt[2 * tid + 1];
    int pair = a0 + a1;
    ss[tid] = pair;
    __syncthreads();
    for (int o = 1; o < 256; o <<= 1) {
        int tv = (tid >= o) ? ss[tid - o] : 0;
        __syncthreads();
        ss[tid] += tv;
        __syncthreads();
    }
    int ep = ss[tid] - pair;
    npre[2 * tid] = ep;
    npre[2 * tid + 1] = ep + a0;
    __syncthreads();
    // offs + invd (coalesced), using counts before they become cursors
#pragma unroll
    for (int q = 0; q < 2; q++) {
        int ln = q * 256 + tid;
        int node = b * BUK + ln;
        if (node < N) {
            offs[node] = base + npre[ln];
            int dg = ncnt[ln];
            invd[node] = 1.0f / (float)(dg > 1 ? dg : 1);
        }
    }
    __syncthreads();
    ncnt[2 * tid] = npre[2 * tid];
    ncnt[2 * tid + 1] = npre[2 * tid + 1];
    __syncthreads();
    for (int i = tid; i < cnt; i += 256) {
        uint pk = eb[i];
        int p = atomicAdd(&ncnt[pk >> 17], 1);
        csrbuf[p] = (int)(pk & 0x1FFFFu);
    }
    __syncthreads();
    for (int i = tid; i < cnt; i += 256) csr[base + i] = csrbuf[i];
    if (b == nbuk - 1 && tid == 0) offs[N] = base + cnt;
}

// ---------------- weight packing: [Wl;Wr] -> bf16 MFMA B-frag layout ----------------

__global__ __launch_bounds__(256) void prep_w_k(
    const float* __restrict__ Wl, const float* __restrict__ Wr, ushort* __restrict__ Bp) {
    int gid = blockIdx.x * 256 + threadIdx.x;    // 3*32768 total
    int layer = gid >> 15;
    int r = gid & 32767;
    int j = r & 7;
    int lane = (r >> 3) & 63;
    int ct = (r >> 9) & 7;
    int ks = r >> 12;
    int k = ks * 32 + (lane >> 4) * 8 + j;
    int n = ct * 16 + (lane & 15);
    float v = (k < HH) ? Wl[(size_t)layer * HH * HH + k * HH + n]
                       : Wr[(size_t)layer * HH * HH + (k - HH) * HH + n];
    Bp[gid] = f2bf(v);
}

// ---------------- node encoder: h = relu(x @ encW + encb), fp32 + bf16 mirror ----------------

__global__ __launch_bounds__(256) void encoder_k(
    const float* __restrict__ x, const float* __restrict__ W,
    const float* __restrict__ b, float* __restrict__ h, uint* __restrict__ hb, int N) {
    int n = blockIdx.x * 4 + (threadIdx.x >> 6);
    int j = threadIdx.x & 63;       // cols 2j, 2j+1
    if (n >= N) return;
    float4 xv = *(const float4*)(x + (size_t)n * 4);
    float v0 = b[2 * j], v1 = b[2 * j + 1];
    v0 = fmaf(xv.x, W[0 * HH + 2 * j], v0); v1 = fmaf(xv.x, W[0 * HH + 2 * j + 1], v1);
    v0 = fmaf(xv.y, W[1 * HH + 2 * j], v0); v1 = fmaf(xv.y, W[1 * HH + 2 * j + 1], v1);
    v0 = fmaf(xv.z, W[2 * HH + 2 * j], v0); v1 = fmaf(xv.z, W[2 * HH + 2 * j + 1], v1);
    v0 = fmaf(xv.w, W[3 * HH + 2 * j], v0); v1 = fmaf(xv.w, W[3 * HH + 2 * j + 1], v1);
    v0 = fmaxf(v0, 0.0f); v1 = fmaxf(v1, 0.0f);
    h[(size_t)n * HH + 2 * j] = v0;
    h[(size_t)n * HH + 2 * j + 1] = v1;
    hb[(size_t)n * 64 + j] = packbf(v0, v1);
}

// ---------------- mean aggregation over in-neighbors (bf16 gather, uint4, 4x unroll) ----------------

__global__ __launch_bounds__(256) void aggregate_k(
    const uint* __restrict__ hb, const int* __restrict__ offs,
    const int* __restrict__ csr, const float* __restrict__ invd,
    uint* __restrict__ aggb, int N) {
    int n = blockIdx.x * 16 + (threadIdx.x >> 4);
    int j = threadIdx.x & 15;     // uint4 -> cols 8j..8j+7
    if (n >= N) return;
    const uint4* hb4 = (const uint4*)hb;
    int s = offs[n], e = offs[n + 1];
    float a0 = 0, a1 = 0, a2 = 0, a3 = 0, a4 = 0, a5 = 0, a6 = 0, a7 = 0;
    int i = s;
    for (; i + 4 <= e; i += 4) {
        int u0 = csr[i], u1 = csr[i + 1], u2 = csr[i + 2], u3 = csr[i + 3];
        uint4 p0 = hb4[(size_t)u0 * 16 + j];
        uint4 p1 = hb4[(size_t)u1 * 16 + j];
        uint4 p2 = hb4[(size_t)u2 * 16 + j];
        uint4 p3 = hb4[(size_t)u3 * 16 + j];
        a0 += (bflo(p0.x) + bflo(p1.x)) + (bflo(p2.x) + bflo(p3.x));
        a1 += (bfhi(p0.x) + bfhi(p1.x)) + (bfhi(p2.x) + bfhi(p3.x));
        a2 += (bflo(p0.y) + bflo(p1.y)) + (bflo(p2.y) + bflo(p3.y));
        a3 += (bfhi(p0.y) + bfhi(p1.y)) + (bfhi(p2.y) + bfhi(p3.y));
        a4 += (bflo(p0.z) + bflo(p1.z)) + (bflo(p2.z) + bflo(p3.z));
        a5 += (bfhi(p0.z) + bfhi(p1.z)) + (bfhi(p2.z) + bfhi(p3.z));
        a6 += (bflo(p0.w) + bflo(p1.w)) + (bflo(p2.w) + bflo(p3.w));
        a7 += (bfhi(p0.w) + bfhi(p1.w)) + (bfhi(p2.w) + bfhi(p3.w));
    }
    for (; i < e; i++) {
        uint4 p = hb4[(size_t)csr[i] * 16 + j];
        a0 += bflo(p.x); a1 += bfhi(p.x);
        a2 += bflo(p.y); a3 += bfhi(p.y);
        a4 += bflo(p.z); a5 += bfhi(p.z);
        a6 += bflo(p.w); a7 += bfhi(p.w);
    }
    float iv = invd[n];
    uint4 o;
    o.x = packbf(a0 * iv, a1 * iv);
    o.y = packbf(a2 * iv, a3 * iv);
    o.z = packbf(a4 * iv, a5 * iv);
    o.w = packbf(a6 * iv, a7 * iv);
    ((uint4*)aggb)[(size_t)n * 16 + j] = o;
}

// ---------------- fused SAGE layer via MFMA bf16 ----------------

__global__ __launch_bounds__(256) void sage_mfma_k(
    const ushort* __restrict__ aggb, float* __restrict__ h, ushort* __restrict__ hb,
    const ushort* __restrict__ Bp, const float* __restrict__ bl,
    const float* __restrict__ g, const float* __restrict__ bln, int N) {
    int wave = threadIdx.x >> 6;
    int lane = threadIdx.x & 63;
    int m0 = blockIdx.x * 128 + wave * 32;

    floatx4 acc[2][8];
#pragma unroll
    for (int rt = 0; rt < 2; rt++)
#pragma unroll
        for (int ct = 0; ct < 8; ct++) acc[rt][ct] = (floatx4)0.0f;

    int am = lane & 15, aq = lane >> 4;
#pragma unroll
    for (int ks = 0; ks < 8; ks++) {
        const ushort* Asrc = (ks < 4) ? aggb : (const ushort*)hb;
        int kc = (ks & 3) * 32 + aq * 8;
        short8 a[2];
#pragma unroll
        for (int rt = 0; rt < 2; rt++) {
            int row = m0 + rt * 16 + am;
            row = row < N ? row : N - 1;
            a[rt] = *(const short8*)(Asrc + (size_t)row * HH + kc);
        }
#pragma unroll
        for (int ct = 0; ct < 8; ct++) {
            short8 b = *(const short8*)(Bp + (((size_t)(ks * 8 + ct)) * 64 + lane) * 8);
            acc[0][ct] = __builtin_amdgcn_mfma_f32_16x16x32_bf16(a[0], b, acc[0][ct], 0, 0, 0);
            acc[1][ct] = __builtin_amdgcn_mfma_f32_16x16x32_bf16(a[1], b, acc[1][ct], 0, 0, 0);
        }
    }

    // epilogue: bias + LN(128) + relu + residual (fp32 master + bf16 mirror)
    int g4 = lane >> 4, cl = lane & 15;
    float bias[8], gam[8], bet[8];
#pragma unroll
    for (int ct = 0; ct < 8; ct++) {
        bias[ct] = bl[ct * 16 + cl];
        gam[ct] = g[ct * 16 + cl];
        bet[ct] = bln[ct * 16 + cl];
    }
#pragma unroll
    for (int rt = 0; rt < 2; rt++) {
        float sr[4], qr[4];
#pragma unroll
        for (int reg = 0; reg < 4; reg++) {
            float s = 0.0f, q = 0.0f;
#pragma unroll
            for (int ct = 0; ct < 8; ct++) {
                float v = acc[rt][ct][reg] + bias[ct];
                s += v;
                q += v * v;
            }
#pragma unroll
            for (int m = 1; m < 16; m <<= 1) {
                s += __shfl_xor(s, m);
                q += __shfl_xor(q, m);
            }
            sr[reg] = s;
            qr[reg] = q;
        }
#pragma unroll
        for (int reg = 0; reg < 4; reg++) {
            int row = m0 + rt * 16 + g4 * 4 + reg;
            if (row < N) {
                float mean = sr[reg] * (1.0f / 128.0f);
                float var = qr[reg] * (1.0f / 128.0f) - mean * mean;
                float rstd = rsqrtf(fmaxf(var, 0.0f) + 1e-5f);
#pragma unroll
                for (int ct = 0; ct < 8; ct++) {
                    float v = acc[rt][ct][reg] + bias[ct];
                    float r = fmaxf((v - mean) * rstd * gam[ct] + bet[ct], 0.0f);
                    size_t idx = (size_t)row * HH + ct * 16 + cl;
                    float nv = h[idx] + r;
                    h[idx] = nv;
                    hb[idx] = f2bf(nv);
                }
            }
        }
    }
}

// ---------------- pooling v3: 256-row chunks, LDS block reduction, few atomics ----------------

__global__ __launch_bounds__(256) void pool_k(
    const uint* __restrict__ hb, const int* __restrict__ batch,
    float* __restrict__ psum, int* __restrict__ pmax, int* __restrict__ pcnt, int N) {
    __shared__ float ls[8][32][4];
    __shared__ float lm[8][32][4];
    int tid = threadIdx.x;
    int lane = tid & 31;   // cols 4*lane .. 4*lane+3
    int slot = tid >> 5;   // 8 row slots
    int n0 = blockIdx.x * 256;
    int nlast = n0 + 255 < N - 1 ? n0 + 255 : N - 1;
    const uint2* hb2 = (const uint2*)hb;
    int b0 = batch[n0];

    if (batch[nlast] == b0) {
        // ---- fast path: whole chunk in one graph ----
        float s0 = 0, s1 = 0, s2 = 0, s3 = 0, m0 = 0, m1 = 0, m2 = 0, m3 = 0;
        for (int i = 0; i < 32; i++) {
            int n = n0 + i * 8 + slot;
            if (n < N) {
                uint2 p = hb2[(size_t)n * 32 + lane];
                float v0 = bflo(p.x), v1 = bfhi(p.x), v2 = bflo(p.y), v3 = bfhi(p.y);
                s0 += v0; s1 += v1; s2 += v2; s3 += v3;
                m0 = fmaxf(m0, v0); m1 = fmaxf(m1, v1);
                m2 = fmaxf(m2, v2); m3 = fmaxf(m3, v3);
            }
        }
        ls[slot][lane][0] = s0; ls[slot][lane][1] = s1;
        ls[slot][lane][2] = s2; ls[slot][lane][3] = s3;
        lm[slot][lane][0] = m0; lm[slot][lane][1] = m1;
        lm[slot][lane][2] = m2; lm[slot][lane][3] = m3;
        __syncthreads();
        if (tid < 128) {
            int ln = tid >> 2, c = tid & 3;
            float s = 0.0f, m = 0.0f;
#pragma unroll
            for (int sl = 0; sl < 8; sl++) {
                s += ls[sl][ln][c];
                m = fmaxf(m, lm[sl][ln][c]);
            }
            atomicAdd(&psum[b0 * HH + tid], s);
            atomicMax(&pmax[b0 * HH + tid], __float_as_int(m));
        }
        if (tid == 0) {
            int rows = (N - n0 < 256) ? (N - n0) : 256;
            atomicAdd(&pcnt[b0], rows);
        }
    } else {
        // ---- slow path (graph boundary inside chunk) ----
        int cur = -1, run = 0;
        float s0 = 0, s1 = 0, s2 = 0, s3 = 0, m0 = 0, m1 = 0, m2 = 0, m3 = 0;
        for (int i = 0; i < 32; i++) {
            int n = n0 + i * 8 + slot;
            if (n >= N) break;
            int b = batch[n];
            if (b != cur) {
                if (cur >= 0) {
                    int cb = cur * HH + lane * 4;
                    atomicAdd(&psum[cb + 0], s0);
                    atomicAdd(&psum[cb + 1], s1);
                    atomicAdd(&psum[cb + 2], s2);
                    atomicAdd(&psum[cb + 3], s3);
                    atomicMax(&pmax[cb + 0], __float_as_int(m0));
                    atomicMax(&pmax[cb + 1], __float_as_int(m1));
                    atomicMax(&pmax[cb + 2], __float_as_int(m2));
                    atomicMax(&pmax[cb + 3], __float_as_int(m3));
                    if (lane == 0) atomicAdd(&pcnt[cur], run);
                }
                cur = b;
                s0 = s1 = s2 = s3 = 0.0f;
                m0 = m1 = m2 = m3 = 0.0f;
                run = 0;
            }
            uint2 p = hb2[(size_t)n * 32 + lane];
            float v0 = bflo(p.x), v1 = bfhi(p.x), v2 = bflo(p.y), v3 = bfhi(p.y);
            s0 += v0; s1 += v1; s2 += v2; s3 += v3;
            m0 = fmaxf(m0, v0); m1 = fmaxf(m1, v1);
            m2 = fmaxf(m2, v2); m3 = fmaxf(m3, v3);
            run++;
        }
        if (cur >= 0) {
            int cb = cur * HH + lane * 4;
            atomicAdd(&psum[cb + 0], s0);
            atomicAdd(&psum[cb + 1], s1);
            atomicAdd(&psum[cb + 2], s2);
            atomicAdd(&psum[cb + 3], s3);
            atomicMax(&pmax[cb + 0], __float_as_int(m0));
            atomicMax(&pmax[cb + 1], __float_as_int(m1));
            atomicMax(&pmax[cb + 2], __float_as_int(m2));
            atomicMax(&pmax[cb + 3], __float_as_int(m3));
            if (lane == 0) atomicAdd(&pcnt[cur], run);
        }
    }
}

// ---------------- head: trackster MLP + concat + LN + classifier ----------------

__global__ __launch_bounds__(128) void head_k(
    const float* __restrict__ psum, const float* __restrict__ pmax,
    const int* __restrict__ pcnt, const float* __restrict__ ts,
    const float* __restrict__ tsW1, const float* __restrict__ tsb1,
    const float* __restrict__ tslng, const float* __restrict__ tslnb,
    const float* __restrict__ tsW2, const float* __restrict__ tsb2,
    const float* __restrict__ clng, const float* __restrict__ clnb,
    const float* __restrict__ cW1, const float* __restrict__ cb1,
    const float* __restrict__ cW2, const float* __restrict__ cb2,
    float* __restrict__ out) {
    int b = blockIdx.x;
    int t = threadIdx.x;
    __shared__ float feat[320];
    __shared__ float tn[64];
    __shared__ float zz[128];
    __shared__ float ps[2], pq[2];

    if (t < 64) {
        float v = tsb1[t];
#pragma unroll
        for (int k = 0; k < 3; k++) v = fmaf(ts[b * 3 + k], tsW1[k * 64 + t], v);
        float s = v, q = v * v;
#pragma unroll
        for (int m = 1; m < 64; m <<= 1) {
            s += __shfl_xor(s, m);
            q += __shfl_xor(q, m);
        }
        float mean = s * (1.0f / 64.0f);
        float var = q * (1.0f / 64.0f) - mean * mean;
        float rstd = rsqrtf(fmaxf(var, 0.0f) + 1e-5f);
        tn[t] = fmaxf((v - mean) * rstd * tslng[t] + tslnb[t], 0.0f);
    }
    __syncthreads();
    if (t < 64) {
        float v = tsb2[t];
        for (int k = 0; k < 64; k++) v = fmaf(tn[k], tsW2[k * 64 + t], v);
        feat[256 + t] = v;
    }
    float cntf = (float)(pcnt[b] > 1 ? pcnt[b] : 1);
    feat[t] = psum[b * HH + t] / cntf;
    feat[128 + t] = pmax[b * HH + t];
    __syncthreads();

    float s = 0.0f, q = 0.0f;
    for (int i = t; i < 320; i += 128) {
        float v = feat[i];
        s += v;
        q += v * v;
    }
#pragma unroll
    for (int m = 1; m < 64; m <<= 1) {
        s += __shfl_xor(s, m);
        q += __shfl_xor(q, m);
    }
    if ((t & 63) == 0) { ps[t >> 6] = s; pq[t >> 6] = q; }
    __syncthreads();
    float S = ps[0] + ps[1], Q = pq[0] + pq[1];
    float mean = S * (1.0f / 320.0f);
    float var = Q * (1.0f / 320.0f) - mean * mean;
    float rstd = rsqrtf(fmaxf(var, 0.0f) + 1e-5f);
    for (int i = t; i < 320; i += 128)
        feat[i] = (feat[i] - mean) * rstd * clng[i] + clnb[i];
    __syncthreads();

    {
        float v = cb1[t];
        for (int k = 0; k < 320; k++) v = fmaf(feat[k], cW1[k * HH + t], v);
        zz[t] = fmaxf(v, 0.0f);
    }
    __syncthreads();
    if (t < 8) {
        float v = cb2[t];
        for (int k = 0; k < 128; k++) v = fmaf(zz[k], cW2[k * 8 + t], v);
        out[b * 8 + t] = v;
    }
}

// ---------------- launcher ----------------

extern "C" void kernel_launch(void* const* d_in, const int* in_sizes, int n_in,
                              void* d_out, int out_size, void* d_ws, size_t ws_size,
                              hipStream_t stream) {
    const int N = in_sizes[0] / 4;
    const int E = in_sizes[1] / 2;
    const int B = in_sizes[3] / 3;
    const int nbuk = (N + BUK - 1) >> BUK_SH;   // <= 256 for N <= 131072

    const float* x    = (const float*)d_in[0];
    const int*   ei   = (const int*)d_in[1];
    const int*   srcv = ei;
    const int*   dstv = ei + E;
    const int*   batch = (const int*)d_in[2];
    const float* ts   = (const float*)d_in[3];
    const float* encW = (const float*)d_in[4];
    const float* encb = (const float*)d_in[5];
    const float* sageWl = (const float*)d_in[6];
    const float* sagebl = (const float*)d_in[7];
    const float* sageWr = (const float*)d_in[8];
    const float* lng  = (const float*)d_in[9];
    const float* lnb  = (const float*)d_in[10];
    const float* tsW1 = (const float*)d_in[11];
    const float* tsb1 = (const float*)d_in[12];
    const float* tslng = (const float*)d_in[13];
    const float* tslnb = (const float*)d_in[14];
    const float* tsW2 = (const float*)d_in[15];
    const float* tsb2 = (const float*)d_in[16];
    const float* clng = (const float*)d_in[17];
    const float* clnb = (const float*)d_in[18];
    const float* cW1  = (const float*)d_in[19];
    const float* cb1  = (const float*)d_in[20];
    const float* cW2  = (const float*)d_in[21];
    const float* cb2  = (const float*)d_in[22];
    float* out = (float*)d_out;

    char* w = (char*)d_ws;
    size_t off = 0;
    auto take = [&](size_t bytes) -> void* {
        void* p = w + off;
        off = (off + bytes + 255) & ~(size_t)255;
        return p;
    };
    float* h    = (float*)take((size_t)N * HH * 4);   // fp32 residual master
    uint*  hb   = (uint*)take((size_t)N * HH * 2);    // bf16 mirror
    uint*  aggb = (uint*)take((size_t)N * HH * 2);    // bf16 aggregate
    ushort* Bp  = (ushort*)take((size_t)3 * HH * 2 * HH * 2); // packed weights
    int*   csr  = (int*)take((size_t)E * 4);
    int*   offs = (int*)take((size_t)(N + 1) * 4);
    float* invd = (float*)take((size_t)N * 4);
    uint*  ebuf = (uint*)take((size_t)nbuk * CAP * 4);
    int*   gcur = (int*)take(256 * 4);
    int*   bbase = (int*)take(256 * 4);
    float* psum = (float*)take((size_t)B * HH * 4);
    int*   pmax = (int*)take((size_t)B * HH * 4);
    int*   pcnt = (int*)take((size_t)B * 4);

    hipMemsetAsync(gcur, 0, 256 * 4, stream);
    hipMemsetAsync(psum, 0, (size_t)B * HH * 4, stream);
    hipMemsetAsync(pmax, 0, (size_t)B * HH * 4, stream);
    hipMemsetAsync(pcnt, 0, (size_t)B * 4, stream);

    bin_k<<<(E + 2047) / 2048, 256, 0, stream>>>(srcv, dstv, gcur, ebuf, E);
    bscan_k<<<1, 256, 0, stream>>>(gcur, bbase, nbuk);
    build_k<<<nbuk, 256, 0, stream>>>(ebuf, gcur, bbase, offs, invd, csr, N, nbuk);

    prep_w_k<<<384, 256, 0, stream>>>(sageWl, sageWr, Bp);
    encoder_k<<<(N + 3) / 4, 256, 0, stream>>>(x, encW, encb, h, hb, N);

    for (int l = 0; l < 3; l++) {
        aggregate_k<<<(N + 15) / 16, 256, 0, stream>>>(hb, offs, csr, invd, aggb, N);
        sage_mfma_k<<<(N + 127) / 128, 256, 0, stream>>>(
            (const ushort*)aggb, h, (ushort*)hb, Bp + (size_t)l * 32768,
            sagebl + (size_t)l * HH, lng + (size_t)l * HH, lnb + (size_t)l * HH, N);
    }

    pool_k<<<(N + 255) / 256, 256, 0, stream>>>(hb, batch, psum, pmax, pcnt, N);
    head_k<<<B, 128, 0, stream>>>(psum, (const float*)pmax, pcnt, ts,
                                  tsW1, tsb1, tslng, tslnb, tsW2, tsb2,
                                  clng, clnb, cW1, cb1, cW2, cb2, out);
}